// Round 16
// baseline (83.966 us; speedup 1.0000x reference)
//
#include <hip/hip_runtime.h>

#define N_NODES   50000
#define N_EDGES   400000
#define IN_NODE   16
#define OUT_NODE  20
#define IN_EDGE   10
#define HE        64
#define HA        256
#define N_ACT     16
#define N_GRAPHS  128
#define BN_EPS    1e-5f
#define HNST      68          // LDS row stride (shorts) for hnT/xT
#define SPLIT     16          // S-kernel blocks per graph
#define NB        1563        // count/scatter blocks: 1563*256 >= N_EDGES
#define NCH       25          // colscan chunks: 25*64 >= NB
#define GB        256         // gram blocks
#define XB        196         // xsum blocks: 196*256 >= N_NODES

typedef __attribute__((ext_vector_type(8))) short short8v;
typedef __attribute__((ext_vector_type(4))) float f32x4;

__device__ __forceinline__ unsigned short f2bf(float f) {
  unsigned u = __float_as_uint(f);
  u += 0x7fffu + ((u >> 16) & 1u);  // RNE
  return (unsigned short)(u >> 16);
}
__device__ __forceinline__ float bf2f(short s) {
  return __uint_as_float(((unsigned)(unsigned short)s) << 16);
}

#define DPP_ROR_ADD(v, CTRL)                                                  \
  ((v) + __int_as_float(__builtin_amdgcn_update_dpp(                          \
             0, __float_as_int(v), (CTRL), 0xF, 0xF, true)))
#define ROW_SUM16(v)                                                          \
  do {                                                                        \
    v = DPP_ROR_ADD(v, 0x128);                                                \
    v = DPP_ROR_ADD(v, 0x124);                                                \
    v = DPP_ROR_ADD(v, 0x122);                                                \
    v = DPP_ROR_ADD(v, 0x121);                                                \
  } while (0)

// ---------------------------------------------------------------------------
// Kernel 0: zero the small accumulator region (hdr, XN, cnt).
// ---------------------------------------------------------------------------
__global__ void zero_k(float* __restrict__ ws) {
  ws[blockIdx.x * 256 + threadIdx.x] = 0.f;
}

// ---------------------------------------------------------------------------
// Kernel 1 (gram ∥ count in ONE dispatch; R15-proven).
// Blocks [0,GB): Gram stats of ea -> hdr (grid-stride, 256-block shape).
// Blocks [GB,GB+NB): per-block per-graph counts; ge[e]; cnt2dT plain stores.
// ---------------------------------------------------------------------------
__global__ __launch_bounds__(256) void gramcount_k(
    const float* __restrict__ ea, const int* __restrict__ ei,
    const int* __restrict__ batch, float* __restrict__ hdr,
    int* __restrict__ ge, int* __restrict__ cnt2dT) {
  __shared__ float red[4][72];
  __shared__ int lh[N_GRAPHS];
  const int tid = threadIdx.x;

  if (blockIdx.x < GB) {
    float cs[10];
    float gm[55];
#pragma unroll
    for (int a = 0; a < 10; ++a) cs[a] = 0.f;
#pragma unroll
    for (int u = 0; u < 55; ++u) gm[u] = 0.f;

    for (int e = blockIdx.x * 256 + tid; e < N_EDGES; e += GB * 256) {
      const float2* rp = reinterpret_cast<const float2*>(ea + (size_t)e * 10);
      float f[10];
#pragma unroll
      for (int p = 0; p < 5; ++p) {
        const float2 t = rp[p];
        f[2 * p] = t.x;
        f[2 * p + 1] = t.y;
      }
#pragma unroll
      for (int a = 0; a < 10; ++a) cs[a] += f[a];
      int idx = 0;
#pragma unroll
      for (int a = 0; a < 10; ++a)
#pragma unroll
        for (int b = a; b < 10; ++b) {
          gm[idx] = fmaf(f[a], f[b], gm[idx]);
          ++idx;
        }
    }

#pragma unroll
    for (int v = 0; v < 10; ++v)
#pragma unroll
      for (int off = 1; off < 64; off <<= 1)
        cs[v] += __shfl_xor(cs[v], off, 64);
#pragma unroll
    for (int u = 0; u < 55; ++u)
#pragma unroll
      for (int off = 1; off < 64; off <<= 1)
        gm[u] += __shfl_xor(gm[u], off, 64);

    const int lane = tid & 63;
    const int w = tid >> 6;
    if (lane == 0) {
#pragma unroll
      for (int v = 0; v < 10; ++v) red[w][v] = cs[v];
#pragma unroll
      for (int u = 0; u < 55; ++u) red[w][10 + u] = gm[u];
    }
    __syncthreads();
    if (tid < 65) {
      const float s = red[0][tid] + red[1][tid] + red[2][tid] + red[3][tid];
      const int dst = (tid < 10) ? tid : 6 + tid;  // gram at hdr[16+..]
      atomicAdd(&hdr[dst], s);
    }
    return;
  }

  const int b = blockIdx.x - GB;
  const int e = b * 256 + tid;
  if (tid < N_GRAPHS) lh[tid] = 0;
  __syncthreads();
  if (e < N_EDGES) {
    const int g = batch[ei[N_EDGES + e]];
    ge[e] = g;
    atomicAdd(&lh[g], 1);
  }
  __syncthreads();
  if (tid < N_GRAPHS) cnt2dT[tid * NB + b] = lh[tid];
}

// ---------------------------------------------------------------------------
// Kernel 2 (colscan ∥ BN-finalize; R15-proven). Blocks [0,128): colscan of
// cnt2dT rows (register-preloaded). Block 128: BN finalize from hdr.
// ---------------------------------------------------------------------------
__global__ __launch_bounds__(128) void colscanfin_k(
    const int* __restrict__ cnt2dT, int* __restrict__ off2dT,
    int* __restrict__ hist, const float* __restrict__ hdr,
    const float* __restrict__ W1, const float* __restrict__ b1,
    const float* __restrict__ gamma, const float* __restrict__ beta,
    float* __restrict__ scale, float* __restrict__ c1out) {
  const int t = threadIdx.x;
  if (blockIdx.x < N_GRAPHS) {
    if (t >= 64) return;
    const int g = blockIdx.x;
    int vals[NCH];
#pragma unroll
    for (int c = 0; c < NCH; ++c) {
      const int b = c * 64 + t;
      vals[c] = (b < NB) ? cnt2dT[g * NB + b] : 0;
    }
    int running = 0;
#pragma unroll
    for (int c = 0; c < NCH; ++c) {
      int s = vals[c];
#pragma unroll
      for (int off = 1; off < 64; off <<= 1) {
        const int y = __shfl_up(s, off, 64);
        if (t >= off) s += y;
      }
      const int b = c * 64 + t;
      if (b < NB) off2dT[g * NB + b] = running + s - vals[c];  // exclusive
      running += __shfl(s, 63, 64);
    }
    if (t == 0) hist[g] = running;
    return;
  }

  if (t < HE) {
    const int c = t;
    float wc[10];
#pragma unroll
    for (int k = 0; k < 10; ++k) wc[k] = W1[k * HE + c];
    float su = 0.f;
#pragma unroll
    for (int k = 0; k < 10; ++k) su = fmaf(hdr[k], wc[k], su);
    float q = 0.f;
    int idx = 0;
#pragma unroll
    for (int a = 0; a < 10; ++a) {
      q = fmaf(hdr[16 + idx], wc[a] * wc[a], q);
      ++idx;
#pragma unroll
      for (int b = a + 1; b < 10; ++b) {
        q = fmaf(2.f * hdr[16 + idx], wc[a] * wc[b], q);
        ++idx;
      }
    }
    const float b1c = b1[c];
    const float invE = 1.f / (float)N_EDGES;
    const float mu = su * invE + b1c;
    const float Eh2 = (q + 2.f * b1c * su) * invE + b1c * b1c;
    const float var = Eh2 - mu * mu;
    const float sc = gamma[c] * rsqrtf(var + BN_EPS);
    scale[c] = sc;
    c1out[c] = sc * (b1c - mu) + beta[c];
  }
}

// ---------------------------------------------------------------------------
// Kernel 3: exclusive scan of hist -> bstart[129]. 1 block, 128 thr.
// ---------------------------------------------------------------------------
__global__ void scan_k(const int* __restrict__ hist,
                       int* __restrict__ bstart) {
  __shared__ int v[N_GRAPHS];
  const int t = threadIdx.x;
  const int h = hist[t];
  v[t] = h;
  __syncthreads();
  for (int off = 1; off < N_GRAPHS; off <<= 1) {
    int y = 0;
    if (t >= off) y = v[t - off];
    __syncthreads();
    v[t] += y;
    __syncthreads();
  }
  bstart[t] = v[t] - h;
  if (t == N_GRAPHS - 1) bstart[N_GRAPHS] = v[t];
}

// ---------------------------------------------------------------------------
// Kernel 4 (scatter ∥ xsum; R15-proven).
// Blocks [0,NB): deterministic scatter-pack -> exb.
// Blocks [NB,NB+XB): xsum (XN, cnt).
// ---------------------------------------------------------------------------
__global__ __launch_bounds__(256) void scatxsum_k(
    const float* __restrict__ ea, const int* __restrict__ ei,
    const int* __restrict__ ge, const float* __restrict__ x,
    const int* __restrict__ off2dT, const int* __restrict__ bstart,
    unsigned short* __restrict__ exb, const int* __restrict__ batch,
    float* __restrict__ XN, float* __restrict__ cnt) {
  const int tid = threadIdx.x;
  if (blockIdx.x < NB) {
    __shared__ int lh[N_GRAPHS];
    __shared__ int obase[N_GRAPHS];
    const int b = blockIdx.x;
    const int e = b * 256 + tid;
    if (tid < N_GRAPHS) lh[tid] = 0;
    __syncthreads();
    int g = -1, r = 0;
    if (e < N_EDGES) {
      g = ge[e];
      r = atomicAdd(&lh[g], 1);
    }
    if (tid < N_GRAPHS) obase[tid] = bstart[tid] + off2dT[tid * NB + b];
    __syncthreads();
    if (e >= N_EDGES) return;

    const float2* rp = reinterpret_cast<const float2*>(ea + (size_t)e * 10);
    float f[10];
#pragma unroll
    for (int p = 0; p < 5; ++p) {
      const float2 t2 = rp[p];
      f[2 * p] = t2.x;
      f[2 * p + 1] = t2.y;
    }
    const int s = ei[e];
    const float4* xp = reinterpret_cast<const float4*>(&x[(size_t)s * IN_NODE]);
    const float4 x0 = xp[0], x1 = xp[1], x2 = xp[2], x3 = xp[3];

    unsigned u[16];
    u[0] = f2bf(f[0]) | ((unsigned)f2bf(f[1]) << 16);
    u[1] = f2bf(f[2]) | ((unsigned)f2bf(f[3]) << 16);
    u[2] = f2bf(f[4]) | ((unsigned)f2bf(f[5]) << 16);
    u[3] = f2bf(f[6]) | ((unsigned)f2bf(f[7]) << 16);
    u[4] = f2bf(f[8]) | ((unsigned)f2bf(f[9]) << 16);
    u[5] = 0; u[6] = 0; u[7] = 0;
    u[8]  = f2bf(x0.x) | ((unsigned)f2bf(x0.y) << 16);
    u[9]  = f2bf(x0.z) | ((unsigned)f2bf(x0.w) << 16);
    u[10] = f2bf(x1.x) | ((unsigned)f2bf(x1.y) << 16);
    u[11] = f2bf(x1.z) | ((unsigned)f2bf(x1.w) << 16);
    u[12] = f2bf(x2.x) | ((unsigned)f2bf(x2.y) << 16);
    u[13] = f2bf(x2.z) | ((unsigned)f2bf(x2.w) << 16);
    u[14] = f2bf(x3.x) | ((unsigned)f2bf(x3.y) << 16);
    u[15] = f2bf(x3.z) | ((unsigned)f2bf(x3.w) << 16);

    const int pos = obase[g] + r;
    int4* dst = reinterpret_cast<int4*>(exb + (size_t)pos * 32);
    dst[0] = int4{(int)u[0], (int)u[1], (int)u[2], (int)u[3]};
    dst[1] = int4{(int)u[4], (int)u[5], (int)u[6], (int)u[7]};
    dst[2] = int4{(int)u[8], (int)u[9], (int)u[10], (int)u[11]};
    dst[3] = int4{(int)u[12], (int)u[13], (int)u[14], (int)u[15]};
    return;
  }

  // ---- xsum part ----
  __shared__ float xn_l[N_GRAPHS * IN_NODE];
  __shared__ float cnt_l[N_GRAPHS];
  const int lane = tid & 63;
  for (int t = tid; t < N_GRAPHS * IN_NODE; t += 256) xn_l[t] = 0.f;
  if (tid < N_GRAPHS) cnt_l[tid] = 0.f;
  __syncthreads();

  const int n = (blockIdx.x - NB) * 256 + tid;
  const bool valid = n < N_NODES;
  int g = -1;
  float xf[IN_NODE];
  if (valid) {
    g = batch[n];
    const float4* xp = reinterpret_cast<const float4*>(&x[(size_t)n * IN_NODE]);
    const float4 a0 = xp[0], a1 = xp[1], a2 = xp[2], a3 = xp[3];
    xf[0] = a0.x;  xf[1] = a0.y;  xf[2] = a0.z;  xf[3] = a0.w;
    xf[4] = a1.x;  xf[5] = a1.y;  xf[6] = a1.z;  xf[7] = a1.w;
    xf[8] = a2.x;  xf[9] = a2.y;  xf[10] = a2.z; xf[11] = a2.w;
    xf[12] = a3.x; xf[13] = a3.y; xf[14] = a3.z; xf[15] = a3.w;
  } else {
#pragma unroll
    for (int i = 0; i < IN_NODE; ++i) xf[i] = 0.f;
  }

  const int g0 = __builtin_amdgcn_readfirstlane(g);
  const bool uni = (__ballot(valid && (g == g0)) == 0xFFFFFFFFFFFFFFFFull);

  if (uni) {
#pragma unroll
    for (int i = 0; i < IN_NODE; ++i) {
      float s = xf[i];
      ROW_SUM16(s);
      s += __shfl_xor(s, 16, 64);
      s += __shfl_xor(s, 32, 64);
      xf[i] = s;
    }
    if (lane == 0) {
#pragma unroll
      for (int i = 0; i < IN_NODE; ++i)
        atomicAdd(&xn_l[g0 * IN_NODE + i], xf[i]);
      atomicAdd(&cnt_l[g0], 64.f);
    }
  } else if (valid) {
#pragma unroll
    for (int i = 0; i < IN_NODE; ++i) atomicAdd(&xn_l[g * IN_NODE + i], xf[i]);
    atomicAdd(&cnt_l[g], 1.f);
  }
  __syncthreads();

  if (tid < N_GRAPHS && cnt_l[tid] != 0.f) atomicAdd(&cnt[tid], cnt_l[tid]);
  for (int t = tid; t < N_GRAPHS * IN_NODE; t += 256) {
    const float v = xn_l[t];
    if (v != 0.f) atomicAdd(&XN[t], v);
  }
}

// ---------------------------------------------------------------------------
// Kernel 5: S accumulation. R16: __launch_bounds__(256,4) -- VGPR=48,
// LDS=21.8KB allow 4 resident blocks/CU (was hinted 2); doubles the
// latency-hiding TLP for the exb-load + barrier critical path.
// ---------------------------------------------------------------------------
__global__ __launch_bounds__(256, 4) void s_kernel(
    const unsigned short* __restrict__ exb, const float* __restrict__ W1g,
    const float* __restrict__ scale, const float* __restrict__ c1g,
    const int* __restrict__ bstart, float* __restrict__ Spart,
    float* __restrict__ XSpart) {
  __shared__ short hnT[2][64 * HNST];  // [c][e]
  __shared__ short xT[2][16 * HNST];   // [i][e]
  __shared__ float scs[HE], c1s[HE];

  const int tid = threadIdx.x;
  const int lane = tid & 63;
  const int w = tid >> 6;
  const int i_col = lane & 15;
  const int kq = lane >> 4;

  if (tid < HE) {
    scs[tid] = scale[tid];
    c1s[tid] = c1g[tid];
  }
  __syncthreads();

  const int g = blockIdx.x / SPLIT;
  const int pp = blockIdx.x - g * SPLIT;
  const int gs = bstart[g], geE = bstart[g + 1];
  const int cnt = geE - gs;
  const int p0 = gs + (cnt * pp) / SPLIT;
  const int p1 = gs + (cnt * (pp + 1)) / SPLIT;

  short8v w1f[4];
  float scv[4], c1v[4];
#pragma unroll
  for (int nt = 0; nt < 4; ++nt) {
    short8v v;
#pragma unroll
    for (int j = 0; j < 8; ++j) {
      const int k = kq * 8 + j;
      const float f = (k < IN_EDGE) ? W1g[k * HE + nt * 16 + i_col] : 0.f;
      v[j] = (short)f2bf(f);
    }
    w1f[nt] = v;
    scv[nt] = scs[nt * 16 + i_col];
    c1v[nt] = c1s[nt * 16 + i_col];
  }

  f32x4 acc = {0.f, 0.f, 0.f, 0.f};
  float xs = 0.f;

  int p = 0;
  for (int base = p0; base < p1; base += 64) {
    {
      const int er = base + w * 16 + i_col;
      short8v ae;
      if (kq < 2) {
        ae = *reinterpret_cast<const short8v*>(&exb[(size_t)er * 32 + kq * 8]);
      } else {
#pragma unroll
        for (int j = 0; j < 8; ++j) ae[j] = 0;
      }
      const f32x4 zero4 = {0.f, 0.f, 0.f, 0.f};
#pragma unroll
      for (int nt = 0; nt < 4; ++nt) {
        const f32x4 hv = __builtin_amdgcn_mfma_f32_16x16x32_bf16(
            ae, w1f[nt], zero4, 0, 0, 0);
        short4 sv;
        {
          const int e0 = base + w * 16 + kq * 4;
          const float h0 = (e0 + 0 < p1) ? fmaxf(fmaf(hv[0], scv[nt], c1v[nt]), 0.f) : 0.f;
          const float h1 = (e0 + 1 < p1) ? fmaxf(fmaf(hv[1], scv[nt], c1v[nt]), 0.f) : 0.f;
          const float h2 = (e0 + 2 < p1) ? fmaxf(fmaf(hv[2], scv[nt], c1v[nt]), 0.f) : 0.f;
          const float h3 = (e0 + 3 < p1) ? fmaxf(fmaf(hv[3], scv[nt], c1v[nt]), 0.f) : 0.f;
          sv.x = (short)f2bf(h0);
          sv.y = (short)f2bf(h1);
          sv.z = (short)f2bf(h2);
          sv.w = (short)f2bf(h3);
        }
        *reinterpret_cast<short4*>(
            &hnT[p][(nt * 16 + i_col) * HNST + w * 16 + kq * 4]) = sv;
      }
    }
    {
      const int et = tid >> 2, iq = tid & 3;
      const int er = base + et;
      short4 xv = {0, 0, 0, 0};
      if (er < p1)
        xv = *reinterpret_cast<const short4*>(
            &exb[(size_t)er * 32 + 16 + iq * 4]);
      xT[p][(iq * 4 + 0) * HNST + et] = xv.x;
      xT[p][(iq * 4 + 1) * HNST + et] = xv.y;
      xT[p][(iq * 4 + 2) * HNST + et] = xv.z;
      xT[p][(iq * 4 + 3) * HNST + et] = xv.w;
    }
    __syncthreads();
#pragma unroll
    for (int ks = 0; ks < 2; ++ks) {
      const short8v a = *reinterpret_cast<const short8v*>(
          &hnT[p][(w * 16 + i_col) * HNST + ks * 32 + kq * 8]);
      const short8v b = *reinterpret_cast<const short8v*>(
          &xT[p][i_col * HNST + ks * 32 + kq * 8]);
      acc = __builtin_amdgcn_mfma_f32_16x16x32_bf16(a, b, acc, 0, 0, 0);
      if (w == 0) {
#pragma unroll
        for (int j = 0; j < 8; ++j) xs += bf2f(b[j]);
      }
    }
    p ^= 1;
  }

  // coalesced partial writes: lane holds S[c = w*16+kq*4+r][i = i_col]
#pragma unroll
  for (int r = 0; r < 4; ++r)
    Spart[(size_t)blockIdx.x * 1024 + (w * 16 + kq * 4 + r) * 16 + i_col] =
        acc[r];
  if (w == 0) {
    xs += __shfl_xor(xs, 16, 64);
    xs += __shfl_xor(xs, 32, 64);
    if (kq == 0) XSpart[blockIdx.x * 16 + i_col] = xs;
  }
}

// ---------------------------------------------------------------------------
// Kernel 6: fuse (R11-proven, unchanged).
// ---------------------------------------------------------------------------
__global__ __launch_bounds__(256) void fuse_k(
    const float* __restrict__ Spart, const float* __restrict__ XSpart,
    const float* __restrict__ W2g, const float* __restrict__ b2g,
    const float* __restrict__ XN, const float* __restrict__ cnt,
    const float* __restrict__ rootg, const float* __restrict__ biasg,
    const float* __restrict__ A1, const float* __restrict__ ab1,
    const float* __restrict__ A2, const float* __restrict__ ab2,
    float* __restrict__ out) {
  __shared__ float S_l[1024];
  __shared__ float xs_l[16];
  __shared__ float xn_f[16];
  __shared__ float pooled[OUT_NODE];
  __shared__ float a_s[HA];
  __shared__ float red[16][N_ACT];

  const int g = blockIdx.x;
  const int tid = threadIdx.x, lane = tid & 63, w = tid >> 6;

  for (int t = tid; t < 1024; t += 256) {
    float s = 0.f;
#pragma unroll
    for (int q = 0; q < SPLIT; ++q)
      s += Spart[(size_t)(SPLIT * g + q) * 1024 + t];
    S_l[t] = s;
  }
  if (tid < 16) {
    float s = 0.f;
#pragma unroll
    for (int q = 0; q < SPLIT; ++q) s += XSpart[(SPLIT * g + q) * 16 + tid];
    xs_l[tid] = s;
    xn_f[tid] = XN[g * IN_NODE + tid];
  }
  __syncthreads();

  const float invc = 1.f / fmaxf(cnt[g], 1.f);
#pragma unroll
  for (int oi = 0; oi < 5; ++oi) {
    const int o = w * 5 + oi;
    float s = 0.f;
#pragma unroll
    for (int j = 0; j < 16; ++j) {
      const int u = lane + 64 * j;
      const int c = u >> 4, i = u & 15;
      s = fmaf(S_l[u], W2g[c * (IN_NODE * OUT_NODE) + i * OUT_NODE + o], s);
    }
    if (lane < 16) {
      s = fmaf(xs_l[lane], b2g[lane * OUT_NODE + o], s);
      s = fmaf(xn_f[lane], rootg[lane * OUT_NODE + o], s);
    }
    ROW_SUM16(s);
    s += __shfl_xor(s, 16, 64);
    s += __shfl_xor(s, 32, 64);
    if (lane == 0) pooled[o] = s * invc + biasg[o];
  }
  __syncthreads();

  {
    float v = ab1[tid];
#pragma unroll
    for (int k = 0; k < OUT_NODE; ++k)
      v = fmaf(pooled[k], A1[k * HA + tid], v);
    a_s[tid] = fmaxf(v, 0.f);
  }
  __syncthreads();
  {
    const int j = tid & 15, seg = tid >> 4;
    float v = 0.f;
#pragma unroll
    for (int kk = 0; kk < 16; ++kk) {
      const int k = seg * 16 + kk;
      v += a_s[k] * A2[k * N_ACT + j];
    }
    red[seg][j] = v;
  }
  __syncthreads();
  if (tid < N_ACT) {
    float s = ab2[tid];
#pragma unroll
    for (int seg = 0; seg < 16; ++seg) s += red[seg][tid];
    out[g * N_ACT + tid] = s;
  }
}

// ---------------------------------------------------------------------------
extern "C" void kernel_launch(void* const* d_in, const int* in_sizes, int n_in,
                              void* d_out, int out_size, void* d_ws,
                              size_t ws_size, hipStream_t stream) {
  const float* x     = (const float*)d_in[0];
  const int*   ei    = (const int*)d_in[1];
  const float* ea    = (const float*)d_in[2];
  const int*   batch = (const int*)d_in[3];
  const float* W1    = (const float*)d_in[4];
  const float* b1    = (const float*)d_in[5];
  const float* gamma = (const float*)d_in[6];
  const float* beta  = (const float*)d_in[7];
  const float* W2    = (const float*)d_in[8];
  const float* b2    = (const float*)d_in[9];
  const float* root  = (const float*)d_in[10];
  const float* bias  = (const float*)d_in[11];
  const float* A1    = (const float*)d_in[12];
  const float* ab1   = (const float*)d_in[13];
  const float* A2    = (const float*)d_in[14];
  const float* ab2   = (const float*)d_in[15];
  float* out = (float*)d_out;

  float* ws = (float*)d_ws;
  int*   iw = (int*)d_ws;
  // word offsets (R15 layout, verbatim)
  float* hdr     = ws;                 // [0:128)   colsum+gram accum
  float* scale   = ws + 128;           // [128:192)
  float* c1      = ws + 192;           // [192:256)
  float* XN      = ws + 256;           // [256:2304)  128*16
  float* cntb    = ws + 2304;          // [2304:2432)
  // --- zero_k covers words [0, 2560) ---
  int*   bstart  = iw + 2560;          // [2560:2692)
  int*   hist    = iw + 2704;          // [2704:2832)
  int*   cnt2dT  = iw + 2848;          // 128*NB = 200064 -> 202912
  int*   off2dT  = iw + 202912;        // 200064 -> 402976
  float* Spart   = ws + 402976;        // 2048*1024 -> 2500128
  float* XSpart  = ws + 2500128;       // 2048*16  -> 2532896
  unsigned short* exb = (unsigned short*)(iw + 2532896);  // 400064*32 shorts
  int*   ge      = iw + 402976;        // aliases Spart; consumed by scatter
                                       // before s_kernel overwrites (stream)

  zero_k<<<10, 256, 0, stream>>>(ws);
  gramcount_k<<<GB + NB, 256, 0, stream>>>(ea, ei, batch, hdr, ge, cnt2dT);
  colscanfin_k<<<N_GRAPHS + 1, 128, 0, stream>>>(cnt2dT, off2dT, hist, hdr,
                                                 W1, b1, gamma, beta, scale,
                                                 c1);
  scan_k<<<1, 128, 0, stream>>>(hist, bstart);
  scatxsum_k<<<NB + XB, 256, 0, stream>>>(ea, ei, ge, x, off2dT, bstart, exb,
                                          batch, XN, cntb);
  s_kernel<<<N_GRAPHS * SPLIT, 256, 0, stream>>>(exb, W1, scale, c1, bstart,
                                                 Spart, XSpart);
  fuse_k<<<N_GRAPHS, 256, 0, stream>>>(Spart, XSpart, W2, b2, XN, cntb, root,
                                       bias, A1, ab1, A2, ab2, out);
}

// Round 17
// 81.173 us; speedup vs baseline: 1.0344x; 1.0344x over previous
//
#include <hip/hip_runtime.h>

#define N_NODES   50000
#define N_EDGES   400000
#define IN_NODE   16
#define OUT_NODE  20
#define IN_EDGE   10
#define HE        64
#define HA        256
#define N_ACT     16
#define N_GRAPHS  128
#define BN_EPS    1e-5f
#define HNST      68          // LDS row stride (shorts) for hnT/xT
#define SPLIT     16          // S-kernel blocks per graph
#define NB        782         // count/scatter blocks (2 edges/thread)
#define SEG2      200192      // NB*256; 2 segments cover N_EDGES
#define NCH       13          // colscan chunks: 13*64 >= NB
#define GB        256         // gram blocks
#define XB        196         // xsum blocks: 196*256 >= N_NODES

typedef __attribute__((ext_vector_type(8))) short short8v;
typedef __attribute__((ext_vector_type(4))) float f32x4;

__device__ __forceinline__ unsigned short f2bf(float f) {
  unsigned u = __float_as_uint(f);
  u += 0x7fffu + ((u >> 16) & 1u);  // RNE
  return (unsigned short)(u >> 16);
}
__device__ __forceinline__ float bf2f(short s) {
  return __uint_as_float(((unsigned)(unsigned short)s) << 16);
}

#define DPP_ROR_ADD(v, CTRL)                                                  \
  ((v) + __int_as_float(__builtin_amdgcn_update_dpp(                          \
             0, __float_as_int(v), (CTRL), 0xF, 0xF, true)))
#define ROW_SUM16(v)                                                          \
  do {                                                                        \
    v = DPP_ROR_ADD(v, 0x128);                                                \
    v = DPP_ROR_ADD(v, 0x124);                                                \
    v = DPP_ROR_ADD(v, 0x122);                                                \
    v = DPP_ROR_ADD(v, 0x121);                                                \
  } while (0)

// ---------------------------------------------------------------------------
// Kernel 0: zero the small accumulator region (hdr, XN, cnt).
// ---------------------------------------------------------------------------
__global__ void zero_k(float* __restrict__ ws) {
  ws[blockIdx.x * 256 + threadIdx.x] = 0.f;
}

// ---------------------------------------------------------------------------
// Kernel 1 (gram ∥ count in ONE dispatch).
// Blocks [0,GB): Gram stats of ea -> hdr (grid-stride).
// Blocks [GB,GB+NB): counts, 2 edges/thread (SEG2-strided, R14-proven);
// ge[e] stored; cnt2dT[g][b] plain stores.
// ---------------------------------------------------------------------------
__global__ __launch_bounds__(256) void gramcount_k(
    const float* __restrict__ ea, const int* __restrict__ ei,
    const int* __restrict__ batch, float* __restrict__ hdr,
    int* __restrict__ ge, int* __restrict__ cnt2dT) {
  __shared__ float red[4][72];
  __shared__ int lh[N_GRAPHS];
  const int tid = threadIdx.x;

  if (blockIdx.x < GB) {
    float cs[10];
    float gm[55];
#pragma unroll
    for (int a = 0; a < 10; ++a) cs[a] = 0.f;
#pragma unroll
    for (int u = 0; u < 55; ++u) gm[u] = 0.f;

    for (int e = blockIdx.x * 256 + tid; e < N_EDGES; e += GB * 256) {
      const float2* rp = reinterpret_cast<const float2*>(ea + (size_t)e * 10);
      float f[10];
#pragma unroll
      for (int p = 0; p < 5; ++p) {
        const float2 t = rp[p];
        f[2 * p] = t.x;
        f[2 * p + 1] = t.y;
      }
#pragma unroll
      for (int a = 0; a < 10; ++a) cs[a] += f[a];
      int idx = 0;
#pragma unroll
      for (int a = 0; a < 10; ++a)
#pragma unroll
        for (int b = a; b < 10; ++b) {
          gm[idx] = fmaf(f[a], f[b], gm[idx]);
          ++idx;
        }
    }

#pragma unroll
    for (int v = 0; v < 10; ++v)
#pragma unroll
      for (int off = 1; off < 64; off <<= 1)
        cs[v] += __shfl_xor(cs[v], off, 64);
#pragma unroll
    for (int u = 0; u < 55; ++u)
#pragma unroll
      for (int off = 1; off < 64; off <<= 1)
        gm[u] += __shfl_xor(gm[u], off, 64);

    const int lane = tid & 63;
    const int w = tid >> 6;
    if (lane == 0) {
#pragma unroll
      for (int v = 0; v < 10; ++v) red[w][v] = cs[v];
#pragma unroll
      for (int u = 0; u < 55; ++u) red[w][10 + u] = gm[u];
    }
    __syncthreads();
    if (tid < 65) {
      const float s = red[0][tid] + red[1][tid] + red[2][tid] + red[3][tid];
      const int dst = (tid < 10) ? tid : 6 + tid;  // gram at hdr[16+..]
      atomicAdd(&hdr[dst], s);
    }
    return;
  }

  const int b = blockIdx.x - GB;
  if (tid < N_GRAPHS) lh[tid] = 0;
  __syncthreads();
#pragma unroll
  for (int j = 0; j < 2; ++j) {
    const int e = b * 256 + tid + j * SEG2;
    if (e < N_EDGES) {
      const int g = batch[ei[N_EDGES + e]];
      ge[e] = g;
      atomicAdd(&lh[g], 1);
    }
  }
  __syncthreads();
  if (tid < N_GRAPHS) cnt2dT[tid * NB + b] = lh[tid];
}

// ---------------------------------------------------------------------------
// Kernel 2 (colscan ∥ BN-finalize). Blocks [0,128): colscan of cnt2dT rows
// (register-preloaded). Block 128: BN finalize from hdr.
// ---------------------------------------------------------------------------
__global__ __launch_bounds__(128) void colscanfin_k(
    const int* __restrict__ cnt2dT, int* __restrict__ off2dT,
    int* __restrict__ hist, const float* __restrict__ hdr,
    const float* __restrict__ W1, const float* __restrict__ b1,
    const float* __restrict__ gamma, const float* __restrict__ beta,
    float* __restrict__ scale, float* __restrict__ c1out) {
  const int t = threadIdx.x;
  if (blockIdx.x < N_GRAPHS) {
    if (t >= 64) return;
    const int g = blockIdx.x;
    int vals[NCH];
#pragma unroll
    for (int c = 0; c < NCH; ++c) {
      const int b = c * 64 + t;
      vals[c] = (b < NB) ? cnt2dT[g * NB + b] : 0;
    }
    int running = 0;
#pragma unroll
    for (int c = 0; c < NCH; ++c) {
      int s = vals[c];
#pragma unroll
      for (int off = 1; off < 64; off <<= 1) {
        const int y = __shfl_up(s, off, 64);
        if (t >= off) s += y;
      }
      const int b = c * 64 + t;
      if (b < NB) off2dT[g * NB + b] = running + s - vals[c];  // exclusive
      running += __shfl(s, 63, 64);
    }
    if (t == 0) hist[g] = running;
    return;
  }

  if (t < HE) {
    const int c = t;
    float wc[10];
#pragma unroll
    for (int k = 0; k < 10; ++k) wc[k] = W1[k * HE + c];
    float su = 0.f;
#pragma unroll
    for (int k = 0; k < 10; ++k) su = fmaf(hdr[k], wc[k], su);
    float q = 0.f;
    int idx = 0;
#pragma unroll
    for (int a = 0; a < 10; ++a) {
      q = fmaf(hdr[16 + idx], wc[a] * wc[a], q);
      ++idx;
#pragma unroll
      for (int b = a + 1; b < 10; ++b) {
        q = fmaf(2.f * hdr[16 + idx], wc[a] * wc[b], q);
        ++idx;
      }
    }
    const float b1c = b1[c];
    const float invE = 1.f / (float)N_EDGES;
    const float mu = su * invE + b1c;
    const float Eh2 = (q + 2.f * b1c * su) * invE + b1c * b1c;
    const float var = Eh2 - mu * mu;
    const float sc = gamma[c] * rsqrtf(var + BN_EPS);
    scale[c] = sc;
    c1out[c] = sc * (b1c - mu) + beta[c];
  }
}

// ---------------------------------------------------------------------------
// Kernel 3 (scatter ∥ xsum). R17: bstart computed IN-BLOCK from hist
// (128-entry LDS scan, L2-hot) -- scan_k dispatch eliminated.
// Blocks [0,NB): deterministic scatter-pack, 2 edges/thread -> exb.
// Blocks [NB,NB+XB): xsum (XN, cnt).
// ---------------------------------------------------------------------------
__global__ __launch_bounds__(256) void scatxsum_k(
    const float* __restrict__ ea, const int* __restrict__ ei,
    const int* __restrict__ ge, const float* __restrict__ x,
    const int* __restrict__ off2dT, const int* __restrict__ hist,
    unsigned short* __restrict__ exb, const int* __restrict__ batch,
    float* __restrict__ XN, float* __restrict__ cnt) {
  const int tid = threadIdx.x;
  if (blockIdx.x < NB) {
    __shared__ int lh[N_GRAPHS];
    __shared__ int vtmp[N_GRAPHS];
    __shared__ int obase[N_GRAPHS];
    const int b = blockIdx.x;
    const int h = (tid < N_GRAPHS) ? hist[tid] : 0;
    if (tid < N_GRAPHS) {
      vtmp[tid] = h;
      lh[tid] = 0;
    }
    __syncthreads();
    // in-block exclusive scan of hist -> bstart (R13 scan pattern)
    for (int off = 1; off < N_GRAPHS; off <<= 1) {
      int y = 0;
      if (tid < N_GRAPHS && tid >= off) y = vtmp[tid - off];
      __syncthreads();
      if (tid < N_GRAPHS) vtmp[tid] += y;
      __syncthreads();
    }
    if (tid < N_GRAPHS)
      obase[tid] = (vtmp[tid] - h) + off2dT[tid * NB + b];
    __syncthreads();

    int gj[2], lr[2];
#pragma unroll
    for (int j = 0; j < 2; ++j) {
      const int e = b * 256 + tid + j * SEG2;
      gj[j] = -1;
      lr[j] = 0;
      if (e < N_EDGES) {
        const int g = ge[e];
        gj[j] = g;
        lr[j] = atomicAdd(&lh[g], 1);
      }
    }
    __syncthreads();

#pragma unroll
    for (int j = 0; j < 2; ++j) {
      if (gj[j] < 0) continue;
      const int e = b * 256 + tid + j * SEG2;
      const float2* rp = reinterpret_cast<const float2*>(ea + (size_t)e * 10);
      float f[10];
#pragma unroll
      for (int p = 0; p < 5; ++p) {
        const float2 t2 = rp[p];
        f[2 * p] = t2.x;
        f[2 * p + 1] = t2.y;
      }
      const int s = ei[e];
      const float4* xp =
          reinterpret_cast<const float4*>(&x[(size_t)s * IN_NODE]);
      const float4 x0 = xp[0], x1 = xp[1], x2 = xp[2], x3 = xp[3];

      unsigned u[16];
      u[0] = f2bf(f[0]) | ((unsigned)f2bf(f[1]) << 16);
      u[1] = f2bf(f[2]) | ((unsigned)f2bf(f[3]) << 16);
      u[2] = f2bf(f[4]) | ((unsigned)f2bf(f[5]) << 16);
      u[3] = f2bf(f[6]) | ((unsigned)f2bf(f[7]) << 16);
      u[4] = f2bf(f[8]) | ((unsigned)f2bf(f[9]) << 16);
      u[5] = 0; u[6] = 0; u[7] = 0;
      u[8]  = f2bf(x0.x) | ((unsigned)f2bf(x0.y) << 16);
      u[9]  = f2bf(x0.z) | ((unsigned)f2bf(x0.w) << 16);
      u[10] = f2bf(x1.x) | ((unsigned)f2bf(x1.y) << 16);
      u[11] = f2bf(x1.z) | ((unsigned)f2bf(x1.w) << 16);
      u[12] = f2bf(x2.x) | ((unsigned)f2bf(x2.y) << 16);
      u[13] = f2bf(x2.z) | ((unsigned)f2bf(x2.w) << 16);
      u[14] = f2bf(x3.x) | ((unsigned)f2bf(x3.y) << 16);
      u[15] = f2bf(x3.z) | ((unsigned)f2bf(x3.w) << 16);

      const int pos = obase[gj[j]] + lr[j];
      int4* dst = reinterpret_cast<int4*>(exb + (size_t)pos * 32);
      dst[0] = int4{(int)u[0], (int)u[1], (int)u[2], (int)u[3]};
      dst[1] = int4{(int)u[4], (int)u[5], (int)u[6], (int)u[7]};
      dst[2] = int4{(int)u[8], (int)u[9], (int)u[10], (int)u[11]};
      dst[3] = int4{(int)u[12], (int)u[13], (int)u[14], (int)u[15]};
    }
    return;
  }

  // ---- xsum part ----
  __shared__ float xn_l[N_GRAPHS * IN_NODE];
  __shared__ float cnt_l[N_GRAPHS];
  const int lane = tid & 63;
  for (int t = tid; t < N_GRAPHS * IN_NODE; t += 256) xn_l[t] = 0.f;
  if (tid < N_GRAPHS) cnt_l[tid] = 0.f;
  __syncthreads();

  const int n = (blockIdx.x - NB) * 256 + tid;
  const bool valid = n < N_NODES;
  int g = -1;
  float xf[IN_NODE];
  if (valid) {
    g = batch[n];
    const float4* xp = reinterpret_cast<const float4*>(&x[(size_t)n * IN_NODE]);
    const float4 a0 = xp[0], a1 = xp[1], a2 = xp[2], a3 = xp[3];
    xf[0] = a0.x;  xf[1] = a0.y;  xf[2] = a0.z;  xf[3] = a0.w;
    xf[4] = a1.x;  xf[5] = a1.y;  xf[6] = a1.z;  xf[7] = a1.w;
    xf[8] = a2.x;  xf[9] = a2.y;  xf[10] = a2.z; xf[11] = a2.w;
    xf[12] = a3.x; xf[13] = a3.y; xf[14] = a3.z; xf[15] = a3.w;
  } else {
#pragma unroll
    for (int i = 0; i < IN_NODE; ++i) xf[i] = 0.f;
  }

  const int g0 = __builtin_amdgcn_readfirstlane(g);
  const bool uni = (__ballot(valid && (g == g0)) == 0xFFFFFFFFFFFFFFFFull);

  if (uni) {
#pragma unroll
    for (int i = 0; i < IN_NODE; ++i) {
      float s = xf[i];
      ROW_SUM16(s);
      s += __shfl_xor(s, 16, 64);
      s += __shfl_xor(s, 32, 64);
      xf[i] = s;
    }
    if (lane == 0) {
#pragma unroll
      for (int i = 0; i < IN_NODE; ++i)
        atomicAdd(&xn_l[g0 * IN_NODE + i], xf[i]);
      atomicAdd(&cnt_l[g0], 64.f);
    }
  } else if (valid) {
#pragma unroll
    for (int i = 0; i < IN_NODE; ++i) atomicAdd(&xn_l[g * IN_NODE + i], xf[i]);
    atomicAdd(&cnt_l[g], 1.f);
  }
  __syncthreads();

  if (tid < N_GRAPHS && cnt_l[tid] != 0.f) atomicAdd(&cnt[tid], cnt_l[tid]);
  for (int t = tid; t < N_GRAPHS * IN_NODE; t += 256) {
    const float v = xn_l[t];
    if (v != 0.f) atomicAdd(&XN[t], v);
  }
}

// ---------------------------------------------------------------------------
// Kernel 4: S accumulation. R17: bstart computed in-block from hist
// (scan_k eliminated); body otherwise R16-identical.
// ---------------------------------------------------------------------------
__global__ __launch_bounds__(256, 4) void s_kernel(
    const unsigned short* __restrict__ exb, const float* __restrict__ W1g,
    const float* __restrict__ scale, const float* __restrict__ c1g,
    const int* __restrict__ hist, float* __restrict__ Spart,
    float* __restrict__ XSpart) {
  __shared__ short hnT[2][64 * HNST];  // [c][e]
  __shared__ short xT[2][16 * HNST];   // [i][e]
  __shared__ float scs[HE], c1s[HE];
  __shared__ int vtmp[N_GRAPHS];
  __shared__ int sb[N_GRAPHS + 1];

  const int tid = threadIdx.x;
  const int lane = tid & 63;
  const int w = tid >> 6;
  const int i_col = lane & 15;
  const int kq = lane >> 4;

  if (tid < HE) {
    scs[tid] = scale[tid];
    c1s[tid] = c1g[tid];
  }
  const int h = (tid < N_GRAPHS) ? hist[tid] : 0;
  if (tid < N_GRAPHS) vtmp[tid] = h;
  __syncthreads();
  for (int off = 1; off < N_GRAPHS; off <<= 1) {
    int y = 0;
    if (tid < N_GRAPHS && tid >= off) y = vtmp[tid - off];
    __syncthreads();
    if (tid < N_GRAPHS) vtmp[tid] += y;
    __syncthreads();
  }
  if (tid < N_GRAPHS) {
    sb[tid] = vtmp[tid] - h;
    if (tid == N_GRAPHS - 1) sb[N_GRAPHS] = vtmp[tid];
  }
  __syncthreads();

  const int g = blockIdx.x / SPLIT;
  const int pp = blockIdx.x - g * SPLIT;
  const int gs = sb[g], geE = sb[g + 1];
  const int cnt = geE - gs;
  const int p0 = gs + (cnt * pp) / SPLIT;
  const int p1 = gs + (cnt * (pp + 1)) / SPLIT;

  short8v w1f[4];
  float scv[4], c1v[4];
#pragma unroll
  for (int nt = 0; nt < 4; ++nt) {
    short8v v;
#pragma unroll
    for (int j = 0; j < 8; ++j) {
      const int k = kq * 8 + j;
      const float f = (k < IN_EDGE) ? W1g[k * HE + nt * 16 + i_col] : 0.f;
      v[j] = (short)f2bf(f);
    }
    w1f[nt] = v;
    scv[nt] = scs[nt * 16 + i_col];
    c1v[nt] = c1s[nt * 16 + i_col];
  }

  f32x4 acc = {0.f, 0.f, 0.f, 0.f};
  float xs = 0.f;

  int p = 0;
  for (int base = p0; base < p1; base += 64) {
    {
      const int er = base + w * 16 + i_col;
      short8v ae;
      if (kq < 2) {
        ae = *reinterpret_cast<const short8v*>(&exb[(size_t)er * 32 + kq * 8]);
      } else {
#pragma unroll
        for (int j = 0; j < 8; ++j) ae[j] = 0;
      }
      const f32x4 zero4 = {0.f, 0.f, 0.f, 0.f};
#pragma unroll
      for (int nt = 0; nt < 4; ++nt) {
        const f32x4 hv = __builtin_amdgcn_mfma_f32_16x16x32_bf16(
            ae, w1f[nt], zero4, 0, 0, 0);
        short4 sv;
        {
          const int e0 = base + w * 16 + kq * 4;
          const float h0 = (e0 + 0 < p1) ? fmaxf(fmaf(hv[0], scv[nt], c1v[nt]), 0.f) : 0.f;
          const float h1 = (e0 + 1 < p1) ? fmaxf(fmaf(hv[1], scv[nt], c1v[nt]), 0.f) : 0.f;
          const float h2 = (e0 + 2 < p1) ? fmaxf(fmaf(hv[2], scv[nt], c1v[nt]), 0.f) : 0.f;
          const float h3 = (e0 + 3 < p1) ? fmaxf(fmaf(hv[3], scv[nt], c1v[nt]), 0.f) : 0.f;
          sv.x = (short)f2bf(h0);
          sv.y = (short)f2bf(h1);
          sv.z = (short)f2bf(h2);
          sv.w = (short)f2bf(h3);
        }
        *reinterpret_cast<short4*>(
            &hnT[p][(nt * 16 + i_col) * HNST + w * 16 + kq * 4]) = sv;
      }
    }
    {
      const int et = tid >> 2, iq = tid & 3;
      const int er = base + et;
      short4 xv = {0, 0, 0, 0};
      if (er < p1)
        xv = *reinterpret_cast<const short4*>(
            &exb[(size_t)er * 32 + 16 + iq * 4]);
      xT[p][(iq * 4 + 0) * HNST + et] = xv.x;
      xT[p][(iq * 4 + 1) * HNST + et] = xv.y;
      xT[p][(iq * 4 + 2) * HNST + et] = xv.z;
      xT[p][(iq * 4 + 3) * HNST + et] = xv.w;
    }
    __syncthreads();
#pragma unroll
    for (int ks = 0; ks < 2; ++ks) {
      const short8v a = *reinterpret_cast<const short8v*>(
          &hnT[p][(w * 16 + i_col) * HNST + ks * 32 + kq * 8]);
      const short8v b = *reinterpret_cast<const short8v*>(
          &xT[p][i_col * HNST + ks * 32 + kq * 8]);
      acc = __builtin_amdgcn_mfma_f32_16x16x32_bf16(a, b, acc, 0, 0, 0);
      if (w == 0) {
#pragma unroll
        for (int j = 0; j < 8; ++j) xs += bf2f(b[j]);
      }
    }
    p ^= 1;
  }

  // coalesced partial writes: lane holds S[c = w*16+kq*4+r][i = i_col]
#pragma unroll
  for (int r = 0; r < 4; ++r)
    Spart[(size_t)blockIdx.x * 1024 + (w * 16 + kq * 4 + r) * 16 + i_col] =
        acc[r];
  if (w == 0) {
    xs += __shfl_xor(xs, 16, 64);
    xs += __shfl_xor(xs, 32, 64);
    if (kq == 0) XSpart[blockIdx.x * 16 + i_col] = xs;
  }
}

// ---------------------------------------------------------------------------
// Kernel 5: fuse (unchanged).
// ---------------------------------------------------------------------------
__global__ __launch_bounds__(256) void fuse_k(
    const float* __restrict__ Spart, const float* __restrict__ XSpart,
    const float* __restrict__ W2g, const float* __restrict__ b2g,
    const float* __restrict__ XN, const float* __restrict__ cnt,
    const float* __restrict__ rootg, const float* __restrict__ biasg,
    const float* __restrict__ A1, const float* __restrict__ ab1,
    const float* __restrict__ A2, const float* __restrict__ ab2,
    float* __restrict__ out) {
  __shared__ float S_l[1024];
  __shared__ float xs_l[16];
  __shared__ float xn_f[16];
  __shared__ float pooled[OUT_NODE];
  __shared__ float a_s[HA];
  __shared__ float red[16][N_ACT];

  const int g = blockIdx.x;
  const int tid = threadIdx.x, lane = tid & 63, w = tid >> 6;

  for (int t = tid; t < 1024; t += 256) {
    float s = 0.f;
#pragma unroll
    for (int q = 0; q < SPLIT; ++q)
      s += Spart[(size_t)(SPLIT * g + q) * 1024 + t];
    S_l[t] = s;
  }
  if (tid < 16) {
    float s = 0.f;
#pragma unroll
    for (int q = 0; q < SPLIT; ++q) s += XSpart[(SPLIT * g + q) * 16 + tid];
    xs_l[tid] = s;
    xn_f[tid] = XN[g * IN_NODE + tid];
  }
  __syncthreads();

  const float invc = 1.f / fmaxf(cnt[g], 1.f);
#pragma unroll
  for (int oi = 0; oi < 5; ++oi) {
    const int o = w * 5 + oi;
    float s = 0.f;
#pragma unroll
    for (int j = 0; j < 16; ++j) {
      const int u = lane + 64 * j;
      const int c = u >> 4, i = u & 15;
      s = fmaf(S_l[u], W2g[c * (IN_NODE * OUT_NODE) + i * OUT_NODE + o], s);
    }
    if (lane < 16) {
      s = fmaf(xs_l[lane], b2g[lane * OUT_NODE + o], s);
      s = fmaf(xn_f[lane], rootg[lane * OUT_NODE + o], s);
    }
    ROW_SUM16(s);
    s += __shfl_xor(s, 16, 64);
    s += __shfl_xor(s, 32, 64);
    if (lane == 0) pooled[o] = s * invc + biasg[o];
  }
  __syncthreads();

  {
    float v = ab1[tid];
#pragma unroll
    for (int k = 0; k < OUT_NODE; ++k)
      v = fmaf(pooled[k], A1[k * HA + tid], v);
    a_s[tid] = fmaxf(v, 0.f);
  }
  __syncthreads();
  {
    const int j = tid & 15, seg = tid >> 4;
    float v = 0.f;
#pragma unroll
    for (int kk = 0; kk < 16; ++kk) {
      const int k = seg * 16 + kk;
      v += a_s[k] * A2[k * N_ACT + j];
    }
    red[seg][j] = v;
  }
  __syncthreads();
  if (tid < N_ACT) {
    float s = ab2[tid];
#pragma unroll
    for (int seg = 0; seg < 16; ++seg) s += red[seg][tid];
    out[g * N_ACT + tid] = s;
  }
}

// ---------------------------------------------------------------------------
extern "C" void kernel_launch(void* const* d_in, const int* in_sizes, int n_in,
                              void* d_out, int out_size, void* d_ws,
                              size_t ws_size, hipStream_t stream) {
  const float* x     = (const float*)d_in[0];
  const int*   ei    = (const int*)d_in[1];
  const float* ea    = (const float*)d_in[2];
  const int*   batch = (const int*)d_in[3];
  const float* W1    = (const float*)d_in[4];
  const float* b1    = (const float*)d_in[5];
  const float* gamma = (const float*)d_in[6];
  const float* beta  = (const float*)d_in[7];
  const float* W2    = (const float*)d_in[8];
  const float* b2    = (const float*)d_in[9];
  const float* root  = (const float*)d_in[10];
  const float* bias  = (const float*)d_in[11];
  const float* A1    = (const float*)d_in[12];
  const float* ab1   = (const float*)d_in[13];
  const float* A2    = (const float*)d_in[14];
  const float* ab2   = (const float*)d_in[15];
  float* out = (float*)d_out;

  float* ws = (float*)d_ws;
  int*   iw = (int*)d_ws;
  // word offsets (R15/R16 layout; cnt2dT/off2dT now use less of their slots)
  float* hdr     = ws;                 // [0:128)   colsum+gram accum
  float* scale   = ws + 128;           // [128:192)
  float* c1      = ws + 192;           // [192:256)
  float* XN      = ws + 256;           // [256:2304)  128*16
  float* cntb    = ws + 2304;          // [2304:2432)
  // --- zero_k covers words [0, 2560) ---
  int*   hist    = iw + 2704;          // [2704:2832)
  int*   cnt2dT  = iw + 2848;          // 128*NB = 100096 (slot to 202912)
  int*   off2dT  = iw + 202912;        // 100096 (slot to 402976)
  float* Spart   = ws + 402976;        // 2048*1024 -> 2500128
  float* XSpart  = ws + 2500128;       // 2048*16  -> 2532896
  unsigned short* exb = (unsigned short*)(iw + 2532896);  // 400064*32 shorts
  int*   ge      = iw + 402976;        // aliases Spart; consumed by scatter
                                       // before s_kernel overwrites (stream)

  zero_k<<<10, 256, 0, stream>>>(ws);
  gramcount_k<<<GB + NB, 256, 0, stream>>>(ea, ei, batch, hdr, ge, cnt2dT);
  colscanfin_k<<<N_GRAPHS + 1, 128, 0, stream>>>(cnt2dT, off2dT, hist, hdr,
                                                 W1, b1, gamma, beta, scale,
                                                 c1);
  scatxsum_k<<<NB + XB, 256, 0, stream>>>(ea, ei, ge, x, off2dT, hist, exb,
                                          batch, XN, cntb);
  s_kernel<<<N_GRAPHS * SPLIT, 256, 0, stream>>>(exb, W1, scale, c1, hist,
                                                 Spart, XSpart);
  fuse_k<<<N_GRAPHS, 256, 0, stream>>>(Spart, XSpart, W2, b2, XN, cntb, root,
                                       bias, A1, ab1, A2, ab2, out);
}

// Round 18
// 77.036 us; speedup vs baseline: 1.0900x; 1.0537x over previous
//
#include <hip/hip_runtime.h>

#define N_NODES   50000
#define N_EDGES   400000
#define IN_NODE   16
#define OUT_NODE  20
#define IN_EDGE   10
#define HE        64
#define HA        256
#define N_ACT     16
#define N_GRAPHS  128
#define BN_EPS    1e-5f
#define HNST      68          // LDS row stride (shorts) for hnT/xT
#define SPLIT     8           // S-kernel blocks per graph (R18: 16 -> 8)
#define NB        782         // count/scatter blocks (2 edges/thread)
#define SEG2      200192      // NB*256; 2 segments cover N_EDGES
#define NCH       13          // colscan chunks: 13*64 >= NB
#define GB        256         // gram blocks
#define XB        196         // xsum blocks: 196*256 >= N_NODES

typedef __attribute__((ext_vector_type(8))) short short8v;
typedef __attribute__((ext_vector_type(4))) float f32x4;

__device__ __forceinline__ unsigned short f2bf(float f) {
  unsigned u = __float_as_uint(f);
  u += 0x7fffu + ((u >> 16) & 1u);  // RNE
  return (unsigned short)(u >> 16);
}
__device__ __forceinline__ float bf2f(short s) {
  return __uint_as_float(((unsigned)(unsigned short)s) << 16);
}

#define DPP_ROR_ADD(v, CTRL)                                                  \
  ((v) + __int_as_float(__builtin_amdgcn_update_dpp(                          \
             0, __float_as_int(v), (CTRL), 0xF, 0xF, true)))
#define ROW_SUM16(v)                                                          \
  do {                                                                        \
    v = DPP_ROR_ADD(v, 0x128);                                                \
    v = DPP_ROR_ADD(v, 0x124);                                                \
    v = DPP_ROR_ADD(v, 0x122);                                                \
    v = DPP_ROR_ADD(v, 0x121);                                                \
  } while (0)

// ---------------------------------------------------------------------------
// Kernel 0: zero the small accumulator region (hdr, XN, cnt).
// ---------------------------------------------------------------------------
__global__ void zero_k(float* __restrict__ ws) {
  ws[blockIdx.x * 256 + threadIdx.x] = 0.f;
}

// ---------------------------------------------------------------------------
// Kernel 1 (gram ∥ count in ONE dispatch; R17-proven).
// ---------------------------------------------------------------------------
__global__ __launch_bounds__(256) void gramcount_k(
    const float* __restrict__ ea, const int* __restrict__ ei,
    const int* __restrict__ batch, float* __restrict__ hdr,
    int* __restrict__ ge, int* __restrict__ cnt2dT) {
  __shared__ float red[4][72];
  __shared__ int lh[N_GRAPHS];
  const int tid = threadIdx.x;

  if (blockIdx.x < GB) {
    float cs[10];
    float gm[55];
#pragma unroll
    for (int a = 0; a < 10; ++a) cs[a] = 0.f;
#pragma unroll
    for (int u = 0; u < 55; ++u) gm[u] = 0.f;

    for (int e = blockIdx.x * 256 + tid; e < N_EDGES; e += GB * 256) {
      const float2* rp = reinterpret_cast<const float2*>(ea + (size_t)e * 10);
      float f[10];
#pragma unroll
      for (int p = 0; p < 5; ++p) {
        const float2 t = rp[p];
        f[2 * p] = t.x;
        f[2 * p + 1] = t.y;
      }
#pragma unroll
      for (int a = 0; a < 10; ++a) cs[a] += f[a];
      int idx = 0;
#pragma unroll
      for (int a = 0; a < 10; ++a)
#pragma unroll
        for (int b = a; b < 10; ++b) {
          gm[idx] = fmaf(f[a], f[b], gm[idx]);
          ++idx;
        }
    }

#pragma unroll
    for (int v = 0; v < 10; ++v)
#pragma unroll
      for (int off = 1; off < 64; off <<= 1)
        cs[v] += __shfl_xor(cs[v], off, 64);
#pragma unroll
    for (int u = 0; u < 55; ++u)
#pragma unroll
      for (int off = 1; off < 64; off <<= 1)
        gm[u] += __shfl_xor(gm[u], off, 64);

    const int lane = tid & 63;
    const int w = tid >> 6;
    if (lane == 0) {
#pragma unroll
      for (int v = 0; v < 10; ++v) red[w][v] = cs[v];
#pragma unroll
      for (int u = 0; u < 55; ++u) red[w][10 + u] = gm[u];
    }
    __syncthreads();
    if (tid < 65) {
      const float s = red[0][tid] + red[1][tid] + red[2][tid] + red[3][tid];
      const int dst = (tid < 10) ? tid : 6 + tid;  // gram at hdr[16+..]
      atomicAdd(&hdr[dst], s);
    }
    return;
  }

  const int b = blockIdx.x - GB;
  if (tid < N_GRAPHS) lh[tid] = 0;
  __syncthreads();
#pragma unroll
  for (int j = 0; j < 2; ++j) {
    const int e = b * 256 + tid + j * SEG2;
    if (e < N_EDGES) {
      const int g = batch[ei[N_EDGES + e]];
      ge[e] = g;
      atomicAdd(&lh[g], 1);
    }
  }
  __syncthreads();
  if (tid < N_GRAPHS) cnt2dT[tid * NB + b] = lh[tid];
}

// ---------------------------------------------------------------------------
// Kernel 2 (colscan ∥ BN-finalize; R17-proven).
// ---------------------------------------------------------------------------
__global__ __launch_bounds__(128) void colscanfin_k(
    const int* __restrict__ cnt2dT, int* __restrict__ off2dT,
    int* __restrict__ hist, const float* __restrict__ hdr,
    const float* __restrict__ W1, const float* __restrict__ b1,
    const float* __restrict__ gamma, const float* __restrict__ beta,
    float* __restrict__ scale, float* __restrict__ c1out) {
  const int t = threadIdx.x;
  if (blockIdx.x < N_GRAPHS) {
    if (t >= 64) return;
    const int g = blockIdx.x;
    int vals[NCH];
#pragma unroll
    for (int c = 0; c < NCH; ++c) {
      const int b = c * 64 + t;
      vals[c] = (b < NB) ? cnt2dT[g * NB + b] : 0;
    }
    int running = 0;
#pragma unroll
    for (int c = 0; c < NCH; ++c) {
      int s = vals[c];
#pragma unroll
      for (int off = 1; off < 64; off <<= 1) {
        const int y = __shfl_up(s, off, 64);
        if (t >= off) s += y;
      }
      const int b = c * 64 + t;
      if (b < NB) off2dT[g * NB + b] = running + s - vals[c];  // exclusive
      running += __shfl(s, 63, 64);
    }
    if (t == 0) hist[g] = running;
    return;
  }

  if (t < HE) {
    const int c = t;
    float wc[10];
#pragma unroll
    for (int k = 0; k < 10; ++k) wc[k] = W1[k * HE + c];
    float su = 0.f;
#pragma unroll
    for (int k = 0; k < 10; ++k) su = fmaf(hdr[k], wc[k], su);
    float q = 0.f;
    int idx = 0;
#pragma unroll
    for (int a = 0; a < 10; ++a) {
      q = fmaf(hdr[16 + idx], wc[a] * wc[a], q);
      ++idx;
#pragma unroll
      for (int b = a + 1; b < 10; ++b) {
        q = fmaf(2.f * hdr[16 + idx], wc[a] * wc[b], q);
        ++idx;
      }
    }
    const float b1c = b1[c];
    const float invE = 1.f / (float)N_EDGES;
    const float mu = su * invE + b1c;
    const float Eh2 = (q + 2.f * b1c * su) * invE + b1c * b1c;
    const float var = Eh2 - mu * mu;
    const float sc = gamma[c] * rsqrtf(var + BN_EPS);
    scale[c] = sc;
    c1out[c] = sc * (b1c - mu) + beta[c];
  }
}

// ---------------------------------------------------------------------------
// Kernel 3 (scatter ∥ xsum; R17-proven, in-block bstart scan).
// ---------------------------------------------------------------------------
__global__ __launch_bounds__(256) void scatxsum_k(
    const float* __restrict__ ea, const int* __restrict__ ei,
    const int* __restrict__ ge, const float* __restrict__ x,
    const int* __restrict__ off2dT, const int* __restrict__ hist,
    unsigned short* __restrict__ exb, const int* __restrict__ batch,
    float* __restrict__ XN, float* __restrict__ cnt) {
  const int tid = threadIdx.x;
  if (blockIdx.x < NB) {
    __shared__ int lh[N_GRAPHS];
    __shared__ int vtmp[N_GRAPHS];
    __shared__ int obase[N_GRAPHS];
    const int b = blockIdx.x;
    const int h = (tid < N_GRAPHS) ? hist[tid] : 0;
    if (tid < N_GRAPHS) {
      vtmp[tid] = h;
      lh[tid] = 0;
    }
    __syncthreads();
    for (int off = 1; off < N_GRAPHS; off <<= 1) {
      int y = 0;
      if (tid < N_GRAPHS && tid >= off) y = vtmp[tid - off];
      __syncthreads();
      if (tid < N_GRAPHS) vtmp[tid] += y;
      __syncthreads();
    }
    if (tid < N_GRAPHS)
      obase[tid] = (vtmp[tid] - h) + off2dT[tid * NB + b];
    __syncthreads();

    int gj[2], lr[2];
#pragma unroll
    for (int j = 0; j < 2; ++j) {
      const int e = b * 256 + tid + j * SEG2;
      gj[j] = -1;
      lr[j] = 0;
      if (e < N_EDGES) {
        const int g = ge[e];
        gj[j] = g;
        lr[j] = atomicAdd(&lh[g], 1);
      }
    }
    __syncthreads();

#pragma unroll
    for (int j = 0; j < 2; ++j) {
      if (gj[j] < 0) continue;
      const int e = b * 256 + tid + j * SEG2;
      const float2* rp = reinterpret_cast<const float2*>(ea + (size_t)e * 10);
      float f[10];
#pragma unroll
      for (int p = 0; p < 5; ++p) {
        const float2 t2 = rp[p];
        f[2 * p] = t2.x;
        f[2 * p + 1] = t2.y;
      }
      const int s = ei[e];
      const float4* xp =
          reinterpret_cast<const float4*>(&x[(size_t)s * IN_NODE]);
      const float4 x0 = xp[0], x1 = xp[1], x2 = xp[2], x3 = xp[3];

      unsigned u[16];
      u[0] = f2bf(f[0]) | ((unsigned)f2bf(f[1]) << 16);
      u[1] = f2bf(f[2]) | ((unsigned)f2bf(f[3]) << 16);
      u[2] = f2bf(f[4]) | ((unsigned)f2bf(f[5]) << 16);
      u[3] = f2bf(f[6]) | ((unsigned)f2bf(f[7]) << 16);
      u[4] = f2bf(f[8]) | ((unsigned)f2bf(f[9]) << 16);
      u[5] = 0; u[6] = 0; u[7] = 0;
      u[8]  = f2bf(x0.x) | ((unsigned)f2bf(x0.y) << 16);
      u[9]  = f2bf(x0.z) | ((unsigned)f2bf(x0.w) << 16);
      u[10] = f2bf(x1.x) | ((unsigned)f2bf(x1.y) << 16);
      u[11] = f2bf(x1.z) | ((unsigned)f2bf(x1.w) << 16);
      u[12] = f2bf(x2.x) | ((unsigned)f2bf(x2.y) << 16);
      u[13] = f2bf(x2.z) | ((unsigned)f2bf(x2.w) << 16);
      u[14] = f2bf(x3.x) | ((unsigned)f2bf(x3.y) << 16);
      u[15] = f2bf(x3.z) | ((unsigned)f2bf(x3.w) << 16);

      const int pos = obase[gj[j]] + lr[j];
      int4* dst = reinterpret_cast<int4*>(exb + (size_t)pos * 32);
      dst[0] = int4{(int)u[0], (int)u[1], (int)u[2], (int)u[3]};
      dst[1] = int4{(int)u[4], (int)u[5], (int)u[6], (int)u[7]};
      dst[2] = int4{(int)u[8], (int)u[9], (int)u[10], (int)u[11]};
      dst[3] = int4{(int)u[12], (int)u[13], (int)u[14], (int)u[15]};
    }
    return;
  }

  // ---- xsum part ----
  __shared__ float xn_l[N_GRAPHS * IN_NODE];
  __shared__ float cnt_l[N_GRAPHS];
  const int lane = tid & 63;
  for (int t = tid; t < N_GRAPHS * IN_NODE; t += 256) xn_l[t] = 0.f;
  if (tid < N_GRAPHS) cnt_l[tid] = 0.f;
  __syncthreads();

  const int n = (blockIdx.x - NB) * 256 + tid;
  const bool valid = n < N_NODES;
  int g = -1;
  float xf[IN_NODE];
  if (valid) {
    g = batch[n];
    const float4* xp = reinterpret_cast<const float4*>(&x[(size_t)n * IN_NODE]);
    const float4 a0 = xp[0], a1 = xp[1], a2 = xp[2], a3 = xp[3];
    xf[0] = a0.x;  xf[1] = a0.y;  xf[2] = a0.z;  xf[3] = a0.w;
    xf[4] = a1.x;  xf[5] = a1.y;  xf[6] = a1.z;  xf[7] = a1.w;
    xf[8] = a2.x;  xf[9] = a2.y;  xf[10] = a2.z; xf[11] = a2.w;
    xf[12] = a3.x; xf[13] = a3.y; xf[14] = a3.z; xf[15] = a3.w;
  } else {
#pragma unroll
    for (int i = 0; i < IN_NODE; ++i) xf[i] = 0.f;
  }

  const int g0 = __builtin_amdgcn_readfirstlane(g);
  const bool uni = (__ballot(valid && (g == g0)) == 0xFFFFFFFFFFFFFFFFull);

  if (uni) {
#pragma unroll
    for (int i = 0; i < IN_NODE; ++i) {
      float s = xf[i];
      ROW_SUM16(s);
      s += __shfl_xor(s, 16, 64);
      s += __shfl_xor(s, 32, 64);
      xf[i] = s;
    }
    if (lane == 0) {
#pragma unroll
      for (int i = 0; i < IN_NODE; ++i)
        atomicAdd(&xn_l[g0 * IN_NODE + i], xf[i]);
      atomicAdd(&cnt_l[g0], 64.f);
    }
  } else if (valid) {
#pragma unroll
    for (int i = 0; i < IN_NODE; ++i) atomicAdd(&xn_l[g * IN_NODE + i], xf[i]);
    atomicAdd(&cnt_l[g], 1.f);
  }
  __syncthreads();

  if (tid < N_GRAPHS && cnt_l[tid] != 0.f) atomicAdd(&cnt[tid], cnt_l[tid]);
  for (int t = tid; t < N_GRAPHS * IN_NODE; t += 256) {
    const float v = xn_l[t];
    if (v != 0.f) atomicAdd(&XN[t], v);
  }
}

// ---------------------------------------------------------------------------
// Kernel 4: S accumulation. R18: SPLIT=8 -> 1024 blocks x ~6 tiles each
// (double-buffer actually fills; per-block prologue paid half as often).
// ---------------------------------------------------------------------------
__global__ __launch_bounds__(256, 4) void s_kernel(
    const unsigned short* __restrict__ exb, const float* __restrict__ W1g,
    const float* __restrict__ scale, const float* __restrict__ c1g,
    const int* __restrict__ hist, float* __restrict__ Spart,
    float* __restrict__ XSpart) {
  __shared__ short hnT[2][64 * HNST];  // [c][e]
  __shared__ short xT[2][16 * HNST];   // [i][e]
  __shared__ float scs[HE], c1s[HE];
  __shared__ int vtmp[N_GRAPHS];
  __shared__ int sb[N_GRAPHS + 1];

  const int tid = threadIdx.x;
  const int lane = tid & 63;
  const int w = tid >> 6;
  const int i_col = lane & 15;
  const int kq = lane >> 4;

  if (tid < HE) {
    scs[tid] = scale[tid];
    c1s[tid] = c1g[tid];
  }
  const int h = (tid < N_GRAPHS) ? hist[tid] : 0;
  if (tid < N_GRAPHS) vtmp[tid] = h;
  __syncthreads();
  for (int off = 1; off < N_GRAPHS; off <<= 1) {
    int y = 0;
    if (tid < N_GRAPHS && tid >= off) y = vtmp[tid - off];
    __syncthreads();
    if (tid < N_GRAPHS) vtmp[tid] += y;
    __syncthreads();
  }
  if (tid < N_GRAPHS) {
    sb[tid] = vtmp[tid] - h;
    if (tid == N_GRAPHS - 1) sb[N_GRAPHS] = vtmp[tid];
  }
  __syncthreads();

  const int g = blockIdx.x / SPLIT;
  const int pp = blockIdx.x - g * SPLIT;
  const int gs = sb[g], geE = sb[g + 1];
  const int cnt = geE - gs;
  const int p0 = gs + (cnt * pp) / SPLIT;
  const int p1 = gs + (cnt * (pp + 1)) / SPLIT;

  short8v w1f[4];
  float scv[4], c1v[4];
#pragma unroll
  for (int nt = 0; nt < 4; ++nt) {
    short8v v;
#pragma unroll
    for (int j = 0; j < 8; ++j) {
      const int k = kq * 8 + j;
      const float f = (k < IN_EDGE) ? W1g[k * HE + nt * 16 + i_col] : 0.f;
      v[j] = (short)f2bf(f);
    }
    w1f[nt] = v;
    scv[nt] = scs[nt * 16 + i_col];
    c1v[nt] = c1s[nt * 16 + i_col];
  }

  f32x4 acc = {0.f, 0.f, 0.f, 0.f};
  float xs = 0.f;

  int p = 0;
  for (int base = p0; base < p1; base += 64) {
    {
      const int er = base + w * 16 + i_col;
      short8v ae;
      if (kq < 2) {
        ae = *reinterpret_cast<const short8v*>(&exb[(size_t)er * 32 + kq * 8]);
      } else {
#pragma unroll
        for (int j = 0; j < 8; ++j) ae[j] = 0;
      }
      const f32x4 zero4 = {0.f, 0.f, 0.f, 0.f};
#pragma unroll
      for (int nt = 0; nt < 4; ++nt) {
        const f32x4 hv = __builtin_amdgcn_mfma_f32_16x16x32_bf16(
            ae, w1f[nt], zero4, 0, 0, 0);
        short4 sv;
        {
          const int e0 = base + w * 16 + kq * 4;
          const float h0 = (e0 + 0 < p1) ? fmaxf(fmaf(hv[0], scv[nt], c1v[nt]), 0.f) : 0.f;
          const float h1 = (e0 + 1 < p1) ? fmaxf(fmaf(hv[1], scv[nt], c1v[nt]), 0.f) : 0.f;
          const float h2 = (e0 + 2 < p1) ? fmaxf(fmaf(hv[2], scv[nt], c1v[nt]), 0.f) : 0.f;
          const float h3 = (e0 + 3 < p1) ? fmaxf(fmaf(hv[3], scv[nt], c1v[nt]), 0.f) : 0.f;
          sv.x = (short)f2bf(h0);
          sv.y = (short)f2bf(h1);
          sv.z = (short)f2bf(h2);
          sv.w = (short)f2bf(h3);
        }
        *reinterpret_cast<short4*>(
            &hnT[p][(nt * 16 + i_col) * HNST + w * 16 + kq * 4]) = sv;
      }
    }
    {
      const int et = tid >> 2, iq = tid & 3;
      const int er = base + et;
      short4 xv = {0, 0, 0, 0};
      if (er < p1)
        xv = *reinterpret_cast<const short4*>(
            &exb[(size_t)er * 32 + 16 + iq * 4]);
      xT[p][(iq * 4 + 0) * HNST + et] = xv.x;
      xT[p][(iq * 4 + 1) * HNST + et] = xv.y;
      xT[p][(iq * 4 + 2) * HNST + et] = xv.z;
      xT[p][(iq * 4 + 3) * HNST + et] = xv.w;
    }
    __syncthreads();
#pragma unroll
    for (int ks = 0; ks < 2; ++ks) {
      const short8v a = *reinterpret_cast<const short8v*>(
          &hnT[p][(w * 16 + i_col) * HNST + ks * 32 + kq * 8]);
      const short8v b = *reinterpret_cast<const short8v*>(
          &xT[p][i_col * HNST + ks * 32 + kq * 8]);
      acc = __builtin_amdgcn_mfma_f32_16x16x32_bf16(a, b, acc, 0, 0, 0);
      if (w == 0) {
#pragma unroll
        for (int j = 0; j < 8; ++j) xs += bf2f(b[j]);
      }
    }
    p ^= 1;
  }

  // coalesced partial writes: lane holds S[c = w*16+kq*4+r][i = i_col]
#pragma unroll
  for (int r = 0; r < 4; ++r)
    Spart[(size_t)blockIdx.x * 1024 + (w * 16 + kq * 4 + r) * 16 + i_col] =
        acc[r];
  if (w == 0) {
    xs += __shfl_xor(xs, 16, 64);
    xs += __shfl_xor(xs, 32, 64);
    if (kq == 0) XSpart[blockIdx.x * 16 + i_col] = xs;
  }
}

// ---------------------------------------------------------------------------
// Kernel 5: fuse (unchanged except SPLIT=8 partial loop).
// ---------------------------------------------------------------------------
__global__ __launch_bounds__(256) void fuse_k(
    const float* __restrict__ Spart, const float* __restrict__ XSpart,
    const float* __restrict__ W2g, const float* __restrict__ b2g,
    const float* __restrict__ XN, const float* __restrict__ cnt,
    const float* __restrict__ rootg, const float* __restrict__ biasg,
    const float* __restrict__ A1, const float* __restrict__ ab1,
    const float* __restrict__ A2, const float* __restrict__ ab2,
    float* __restrict__ out) {
  __shared__ float S_l[1024];
  __shared__ float xs_l[16];
  __shared__ float xn_f[16];
  __shared__ float pooled[OUT_NODE];
  __shared__ float a_s[HA];
  __shared__ float red[16][N_ACT];

  const int g = blockIdx.x;
  const int tid = threadIdx.x, lane = tid & 63, w = tid >> 6;

  for (int t = tid; t < 1024; t += 256) {
    float s = 0.f;
#pragma unroll
    for (int q = 0; q < SPLIT; ++q)
      s += Spart[(size_t)(SPLIT * g + q) * 1024 + t];
    S_l[t] = s;
  }
  if (tid < 16) {
    float s = 0.f;
#pragma unroll
    for (int q = 0; q < SPLIT; ++q) s += XSpart[(SPLIT * g + q) * 16 + tid];
    xs_l[tid] = s;
    xn_f[tid] = XN[g * IN_NODE + tid];
  }
  __syncthreads();

  const float invc = 1.f / fmaxf(cnt[g], 1.f);
#pragma unroll
  for (int oi = 0; oi < 5; ++oi) {
    const int o = w * 5 + oi;
    float s = 0.f;
#pragma unroll
    for (int j = 0; j < 16; ++j) {
      const int u = lane + 64 * j;
      const int c = u >> 4, i = u & 15;
      s = fmaf(S_l[u], W2g[c * (IN_NODE * OUT_NODE) + i * OUT_NODE + o], s);
    }
    if (lane < 16) {
      s = fmaf(xs_l[lane], b2g[lane * OUT_NODE + o], s);
      s = fmaf(xn_f[lane], rootg[lane * OUT_NODE + o], s);
    }
    ROW_SUM16(s);
    s += __shfl_xor(s, 16, 64);
    s += __shfl_xor(s, 32, 64);
    if (lane == 0) pooled[o] = s * invc + biasg[o];
  }
  __syncthreads();

  {
    float v = ab1[tid];
#pragma unroll
    for (int k = 0; k < OUT_NODE; ++k)
      v = fmaf(pooled[k], A1[k * HA + tid], v);
    a_s[tid] = fmaxf(v, 0.f);
  }
  __syncthreads();
  {
    const int j = tid & 15, seg = tid >> 4;
    float v = 0.f;
#pragma unroll
    for (int kk = 0; kk < 16; ++kk) {
      const int k = seg * 16 + kk;
      v += a_s[k] * A2[k * N_ACT + j];
    }
    red[seg][j] = v;
  }
  __syncthreads();
  if (tid < N_ACT) {
    float s = ab2[tid];
#pragma unroll
    for (int seg = 0; seg < 16; ++seg) s += red[seg][tid];
    out[g * N_ACT + tid] = s;
  }
}

// ---------------------------------------------------------------------------
extern "C" void kernel_launch(void* const* d_in, const int* in_sizes, int n_in,
                              void* d_out, int out_size, void* d_ws,
                              size_t ws_size, hipStream_t stream) {
  const float* x     = (const float*)d_in[0];
  const int*   ei    = (const int*)d_in[1];
  const float* ea    = (const float*)d_in[2];
  const int*   batch = (const int*)d_in[3];
  const float* W1    = (const float*)d_in[4];
  const float* b1    = (const float*)d_in[5];
  const float* gamma = (const float*)d_in[6];
  const float* beta  = (const float*)d_in[7];
  const float* W2    = (const float*)d_in[8];
  const float* b2    = (const float*)d_in[9];
  const float* root  = (const float*)d_in[10];
  const float* bias  = (const float*)d_in[11];
  const float* A1    = (const float*)d_in[12];
  const float* ab1   = (const float*)d_in[13];
  const float* A2    = (const float*)d_in[14];
  const float* ab2   = (const float*)d_in[15];
  float* out = (float*)d_out;

  float* ws = (float*)d_ws;
  int*   iw = (int*)d_ws;
  // word offsets (R17 layout; Spart/XSpart now half-used)
  float* hdr     = ws;                 // [0:128)
  float* scale   = ws + 128;           // [128:192)
  float* c1      = ws + 192;           // [192:256)
  float* XN      = ws + 256;           // [256:2304)
  float* cntb    = ws + 2304;          // [2304:2432)
  // --- zero_k covers words [0, 2560) ---
  int*   hist    = iw + 2704;          // [2704:2832)
  int*   cnt2dT  = iw + 2848;          // 128*NB = 100096 (slot to 202912)
  int*   off2dT  = iw + 202912;        // 100096 (slot to 402976)
  float* Spart   = ws + 402976;        // 1024*1024 (slot to 2500128)
  float* XSpart  = ws + 2500128;       // 1024*16  (slot to 2532896)
  unsigned short* exb = (unsigned short*)(iw + 2532896);  // 400064*32 shorts
  int*   ge      = iw + 402976;        // aliases Spart; consumed by scatter
                                       // before s_kernel overwrites (stream)

  zero_k<<<10, 256, 0, stream>>>(ws);
  gramcount_k<<<GB + NB, 256, 0, stream>>>(ea, ei, batch, hdr, ge, cnt2dT);
  colscanfin_k<<<N_GRAPHS + 1, 128, 0, stream>>>(cnt2dT, off2dT, hist, hdr,
                                                 W1, b1, gamma, beta, scale,
                                                 c1);
  scatxsum_k<<<NB + XB, 256, 0, stream>>>(ea, ei, ge, x, off2dT, hist, exb,
                                          batch, XN, cntb);
  s_kernel<<<N_GRAPHS * SPLIT, 256, 0, stream>>>(exb, W1, scale, c1, hist,
                                                 Spart, XSpart);
  fuse_k<<<N_GRAPHS, 256, 0, stream>>>(Spart, XSpart, W2, b2, XN, cntb, root,
                                       bias, A1, ab1, A2, ab2, out);
}

// Round 19
// 76.496 us; speedup vs baseline: 1.0977x; 1.0071x over previous
//
#include <hip/hip_runtime.h>

#define N_NODES   50000
#define N_EDGES   400000
#define IN_NODE   16
#define OUT_NODE  20
#define IN_EDGE   10
#define HE        64
#define HA        256
#define N_ACT     16
#define N_GRAPHS  128
#define BN_EPS    1e-5f
#define HNST      68          // LDS row stride (shorts) for hnT/xT
#define SPLIT     8           // S-kernel blocks per graph
#define NB        782         // count/scatter blocks (2 edges/thread)
#define SEG2      200192      // NB*256; 2 segments cover N_EDGES
#define NCH       13          // colscan chunks: 13*64 >= NB
#define GB        256         // gram blocks
#define XB        196         // xsum blocks: 196*256 >= N_NODES

typedef __attribute__((ext_vector_type(8))) short short8v;
typedef __attribute__((ext_vector_type(4))) float f32x4;

__device__ __forceinline__ unsigned short f2bf(float f) {
  unsigned u = __float_as_uint(f);
  u += 0x7fffu + ((u >> 16) & 1u);  // RNE
  return (unsigned short)(u >> 16);
}
__device__ __forceinline__ float bf2f(short s) {
  return __uint_as_float(((unsigned)(unsigned short)s) << 16);
}

#define DPP_ROR_ADD(v, CTRL)                                                  \
  ((v) + __int_as_float(__builtin_amdgcn_update_dpp(                          \
             0, __float_as_int(v), (CTRL), 0xF, 0xF, true)))
#define ROW_SUM16(v)                                                          \
  do {                                                                        \
    v = DPP_ROR_ADD(v, 0x128);                                                \
    v = DPP_ROR_ADD(v, 0x124);                                                \
    v = DPP_ROR_ADD(v, 0x122);                                                \
    v = DPP_ROR_ADD(v, 0x121);                                                \
  } while (0)

// Single-wave 128-entry exclusive scan of hist -> sb[0..128].
// Call with tid < 64 only; caller barriers afterward. 12 shfl steps,
// ZERO internal barriers (replaces the 14-barrier LDS ladder).
__device__ __forceinline__ void wave_scan_hist(const int* __restrict__ hist,
                                               int* __restrict__ sb,
                                               int lane) {
  const int h0 = hist[lane];
  const int h1 = hist[64 + lane];
  int s0 = h0;
#pragma unroll
  for (int off = 1; off < 64; off <<= 1) {
    const int y = __shfl_up(s0, off, 64);
    if (lane >= off) s0 += y;
  }
  const int tot0 = __shfl(s0, 63, 64);
  int s1 = h1;
#pragma unroll
  for (int off = 1; off < 64; off <<= 1) {
    const int y = __shfl_up(s1, off, 64);
    if (lane >= off) s1 += y;
  }
  sb[lane] = s0 - h0;
  sb[64 + lane] = tot0 + s1 - h1;
  if (lane == 63) sb[128] = tot0 + s1;
}

// ---------------------------------------------------------------------------
// Kernel 0: zero the small accumulator region (hdr, XN, cnt).
// ---------------------------------------------------------------------------
__global__ void zero_k(float* __restrict__ ws) {
  ws[blockIdx.x * 256 + threadIdx.x] = 0.f;
}

// ---------------------------------------------------------------------------
// Kernel 1 (gram ∥ count in ONE dispatch; R17-proven).
// ---------------------------------------------------------------------------
__global__ __launch_bounds__(256) void gramcount_k(
    const float* __restrict__ ea, const int* __restrict__ ei,
    const int* __restrict__ batch, float* __restrict__ hdr,
    int* __restrict__ ge, int* __restrict__ cnt2dT) {
  __shared__ float red[4][72];
  __shared__ int lh[N_GRAPHS];
  const int tid = threadIdx.x;

  if (blockIdx.x < GB) {
    float cs[10];
    float gm[55];
#pragma unroll
    for (int a = 0; a < 10; ++a) cs[a] = 0.f;
#pragma unroll
    for (int u = 0; u < 55; ++u) gm[u] = 0.f;

    for (int e = blockIdx.x * 256 + tid; e < N_EDGES; e += GB * 256) {
      const float2* rp = reinterpret_cast<const float2*>(ea + (size_t)e * 10);
      float f[10];
#pragma unroll
      for (int p = 0; p < 5; ++p) {
        const float2 t = rp[p];
        f[2 * p] = t.x;
        f[2 * p + 1] = t.y;
      }
#pragma unroll
      for (int a = 0; a < 10; ++a) cs[a] += f[a];
      int idx = 0;
#pragma unroll
      for (int a = 0; a < 10; ++a)
#pragma unroll
        for (int b = a; b < 10; ++b) {
          gm[idx] = fmaf(f[a], f[b], gm[idx]);
          ++idx;
        }
    }

#pragma unroll
    for (int v = 0; v < 10; ++v)
#pragma unroll
      for (int off = 1; off < 64; off <<= 1)
        cs[v] += __shfl_xor(cs[v], off, 64);
#pragma unroll
    for (int u = 0; u < 55; ++u)
#pragma unroll
      for (int off = 1; off < 64; off <<= 1)
        gm[u] += __shfl_xor(gm[u], off, 64);

    const int lane = tid & 63;
    const int w = tid >> 6;
    if (lane == 0) {
#pragma unroll
      for (int v = 0; v < 10; ++v) red[w][v] = cs[v];
#pragma unroll
      for (int u = 0; u < 55; ++u) red[w][10 + u] = gm[u];
    }
    __syncthreads();
    if (tid < 65) {
      const float s = red[0][tid] + red[1][tid] + red[2][tid] + red[3][tid];
      const int dst = (tid < 10) ? tid : 6 + tid;  // gram at hdr[16+..]
      atomicAdd(&hdr[dst], s);
    }
    return;
  }

  const int b = blockIdx.x - GB;
  if (tid < N_GRAPHS) lh[tid] = 0;
  __syncthreads();
#pragma unroll
  for (int j = 0; j < 2; ++j) {
    const int e = b * 256 + tid + j * SEG2;
    if (e < N_EDGES) {
      const int g = batch[ei[N_EDGES + e]];
      ge[e] = g;
      atomicAdd(&lh[g], 1);
    }
  }
  __syncthreads();
  if (tid < N_GRAPHS) cnt2dT[tid * NB + b] = lh[tid];
}

// ---------------------------------------------------------------------------
// Kernel 2 (colscan ∥ BN-finalize; R17-proven).
// ---------------------------------------------------------------------------
__global__ __launch_bounds__(128) void colscanfin_k(
    const int* __restrict__ cnt2dT, int* __restrict__ off2dT,
    int* __restrict__ hist, const float* __restrict__ hdr,
    const float* __restrict__ W1, const float* __restrict__ b1,
    const float* __restrict__ gamma, const float* __restrict__ beta,
    float* __restrict__ scale, float* __restrict__ c1out) {
  const int t = threadIdx.x;
  if (blockIdx.x < N_GRAPHS) {
    if (t >= 64) return;
    const int g = blockIdx.x;
    int vals[NCH];
#pragma unroll
    for (int c = 0; c < NCH; ++c) {
      const int b = c * 64 + t;
      vals[c] = (b < NB) ? cnt2dT[g * NB + b] : 0;
    }
    int running = 0;
#pragma unroll
    for (int c = 0; c < NCH; ++c) {
      int s = vals[c];
#pragma unroll
      for (int off = 1; off < 64; off <<= 1) {
        const int y = __shfl_up(s, off, 64);
        if (t >= off) s += y;
      }
      const int b = c * 64 + t;
      if (b < NB) off2dT[g * NB + b] = running + s - vals[c];  // exclusive
      running += __shfl(s, 63, 64);
    }
    if (t == 0) hist[g] = running;
    return;
  }

  if (t < HE) {
    const int c = t;
    float wc[10];
#pragma unroll
    for (int k = 0; k < 10; ++k) wc[k] = W1[k * HE + c];
    float su = 0.f;
#pragma unroll
    for (int k = 0; k < 10; ++k) su = fmaf(hdr[k], wc[k], su);
    float q = 0.f;
    int idx = 0;
#pragma unroll
    for (int a = 0; a < 10; ++a) {
      q = fmaf(hdr[16 + idx], wc[a] * wc[a], q);
      ++idx;
#pragma unroll
      for (int b = a + 1; b < 10; ++b) {
        q = fmaf(2.f * hdr[16 + idx], wc[a] * wc[b], q);
        ++idx;
      }
    }
    const float b1c = b1[c];
    const float invE = 1.f / (float)N_EDGES;
    const float mu = su * invE + b1c;
    const float Eh2 = (q + 2.f * b1c * su) * invE + b1c * b1c;
    const float var = Eh2 - mu * mu;
    const float sc = gamma[c] * rsqrtf(var + BN_EPS);
    scale[c] = sc;
    c1out[c] = sc * (b1c - mu) + beta[c];
  }
}

// ---------------------------------------------------------------------------
// Kernel 3 (scatter ∥ xsum). R19: single-wave hist scan (1 barrier, was 14).
// ---------------------------------------------------------------------------
__global__ __launch_bounds__(256) void scatxsum_k(
    const float* __restrict__ ea, const int* __restrict__ ei,
    const int* __restrict__ ge, const float* __restrict__ x,
    const int* __restrict__ off2dT, const int* __restrict__ hist,
    unsigned short* __restrict__ exb, const int* __restrict__ batch,
    float* __restrict__ XN, float* __restrict__ cnt) {
  const int tid = threadIdx.x;
  if (blockIdx.x < NB) {
    __shared__ int lh[N_GRAPHS];
    __shared__ int sb[N_GRAPHS + 1];
    __shared__ int obase[N_GRAPHS];
    const int b = blockIdx.x;
    if (tid < N_GRAPHS) lh[tid] = 0;
    if (tid < 64) wave_scan_hist(hist, sb, tid);
    __syncthreads();
    if (tid < N_GRAPHS) obase[tid] = sb[tid] + off2dT[tid * NB + b];

    int gj[2], lr[2];
#pragma unroll
    for (int j = 0; j < 2; ++j) {
      const int e = b * 256 + tid + j * SEG2;
      gj[j] = -1;
      lr[j] = 0;
      if (e < N_EDGES) {
        const int g = ge[e];
        gj[j] = g;
        lr[j] = atomicAdd(&lh[g], 1);
      }
    }
    __syncthreads();

#pragma unroll
    for (int j = 0; j < 2; ++j) {
      if (gj[j] < 0) continue;
      const int e = b * 256 + tid + j * SEG2;
      const float2* rp = reinterpret_cast<const float2*>(ea + (size_t)e * 10);
      float f[10];
#pragma unroll
      for (int p = 0; p < 5; ++p) {
        const float2 t2 = rp[p];
        f[2 * p] = t2.x;
        f[2 * p + 1] = t2.y;
      }
      const int s = ei[e];
      const float4* xp =
          reinterpret_cast<const float4*>(&x[(size_t)s * IN_NODE]);
      const float4 x0 = xp[0], x1 = xp[1], x2 = xp[2], x3 = xp[3];

      unsigned u[16];
      u[0] = f2bf(f[0]) | ((unsigned)f2bf(f[1]) << 16);
      u[1] = f2bf(f[2]) | ((unsigned)f2bf(f[3]) << 16);
      u[2] = f2bf(f[4]) | ((unsigned)f2bf(f[5]) << 16);
      u[3] = f2bf(f[6]) | ((unsigned)f2bf(f[7]) << 16);
      u[4] = f2bf(f[8]) | ((unsigned)f2bf(f[9]) << 16);
      u[5] = 0; u[6] = 0; u[7] = 0;
      u[8]  = f2bf(x0.x) | ((unsigned)f2bf(x0.y) << 16);
      u[9]  = f2bf(x0.z) | ((unsigned)f2bf(x0.w) << 16);
      u[10] = f2bf(x1.x) | ((unsigned)f2bf(x1.y) << 16);
      u[11] = f2bf(x1.z) | ((unsigned)f2bf(x1.w) << 16);
      u[12] = f2bf(x2.x) | ((unsigned)f2bf(x2.y) << 16);
      u[13] = f2bf(x2.z) | ((unsigned)f2bf(x2.w) << 16);
      u[14] = f2bf(x3.x) | ((unsigned)f2bf(x3.y) << 16);
      u[15] = f2bf(x3.z) | ((unsigned)f2bf(x3.w) << 16);

      const int pos = obase[gj[j]] + lr[j];
      int4* dst = reinterpret_cast<int4*>(exb + (size_t)pos * 32);
      dst[0] = int4{(int)u[0], (int)u[1], (int)u[2], (int)u[3]};
      dst[1] = int4{(int)u[4], (int)u[5], (int)u[6], (int)u[7]};
      dst[2] = int4{(int)u[8], (int)u[9], (int)u[10], (int)u[11]};
      dst[3] = int4{(int)u[12], (int)u[13], (int)u[14], (int)u[15]};
    }
    return;
  }

  // ---- xsum part ----
  __shared__ float xn_l[N_GRAPHS * IN_NODE];
  __shared__ float cnt_l[N_GRAPHS];
  const int lane = tid & 63;
  for (int t = tid; t < N_GRAPHS * IN_NODE; t += 256) xn_l[t] = 0.f;
  if (tid < N_GRAPHS) cnt_l[tid] = 0.f;
  __syncthreads();

  const int n = (blockIdx.x - NB) * 256 + tid;
  const bool valid = n < N_NODES;
  int g = -1;
  float xf[IN_NODE];
  if (valid) {
    g = batch[n];
    const float4* xp = reinterpret_cast<const float4*>(&x[(size_t)n * IN_NODE]);
    const float4 a0 = xp[0], a1 = xp[1], a2 = xp[2], a3 = xp[3];
    xf[0] = a0.x;  xf[1] = a0.y;  xf[2] = a0.z;  xf[3] = a0.w;
    xf[4] = a1.x;  xf[5] = a1.y;  xf[6] = a1.z;  xf[7] = a1.w;
    xf[8] = a2.x;  xf[9] = a2.y;  xf[10] = a2.z; xf[11] = a2.w;
    xf[12] = a3.x; xf[13] = a3.y; xf[14] = a3.z; xf[15] = a3.w;
  } else {
#pragma unroll
    for (int i = 0; i < IN_NODE; ++i) xf[i] = 0.f;
  }

  const int g0 = __builtin_amdgcn_readfirstlane(g);
  const bool uni = (__ballot(valid && (g == g0)) == 0xFFFFFFFFFFFFFFFFull);

  if (uni) {
#pragma unroll
    for (int i = 0; i < IN_NODE; ++i) {
      float s = xf[i];
      ROW_SUM16(s);
      s += __shfl_xor(s, 16, 64);
      s += __shfl_xor(s, 32, 64);
      xf[i] = s;
    }
    if (lane == 0) {
#pragma unroll
      for (int i = 0; i < IN_NODE; ++i)
        atomicAdd(&xn_l[g0 * IN_NODE + i], xf[i]);
      atomicAdd(&cnt_l[g0], 64.f);
    }
  } else if (valid) {
#pragma unroll
    for (int i = 0; i < IN_NODE; ++i) atomicAdd(&xn_l[g * IN_NODE + i], xf[i]);
    atomicAdd(&cnt_l[g], 1.f);
  }
  __syncthreads();

  if (tid < N_GRAPHS && cnt_l[tid] != 0.f) atomicAdd(&cnt[tid], cnt_l[tid]);
  for (int t = tid; t < N_GRAPHS * IN_NODE; t += 256) {
    const float v = xn_l[t];
    if (v != 0.f) atomicAdd(&XN[t], v);
  }
}

// ---------------------------------------------------------------------------
// Kernel 4: S accumulation. R19: single-wave hist scan (1 barrier, was 14);
// body otherwise R18-identical (SPLIT=8).
// ---------------------------------------------------------------------------
__global__ __launch_bounds__(256, 4) void s_kernel(
    const unsigned short* __restrict__ exb, const float* __restrict__ W1g,
    const float* __restrict__ scale, const float* __restrict__ c1g,
    const int* __restrict__ hist, float* __restrict__ Spart,
    float* __restrict__ XSpart) {
  __shared__ short hnT[2][64 * HNST];  // [c][e]
  __shared__ short xT[2][16 * HNST];   // [i][e]
  __shared__ float scs[HE], c1s[HE];
  __shared__ int sb[N_GRAPHS + 1];

  const int tid = threadIdx.x;
  const int lane = tid & 63;
  const int w = tid >> 6;
  const int i_col = lane & 15;
  const int kq = lane >> 4;

  if (tid < HE) {
    scs[tid] = scale[tid];
    c1s[tid] = c1g[tid];
  } else if (tid >= 64 && tid < 128) {
    wave_scan_hist(hist, sb, lane);
  }
  __syncthreads();

  const int g = blockIdx.x / SPLIT;
  const int pp = blockIdx.x - g * SPLIT;
  const int gs = sb[g], geE = sb[g + 1];
  const int cnt = geE - gs;
  const int p0 = gs + (cnt * pp) / SPLIT;
  const int p1 = gs + (cnt * (pp + 1)) / SPLIT;

  short8v w1f[4];
  float scv[4], c1v[4];
#pragma unroll
  for (int nt = 0; nt < 4; ++nt) {
    short8v v;
#pragma unroll
    for (int j = 0; j < 8; ++j) {
      const int k = kq * 8 + j;
      const float f = (k < IN_EDGE) ? W1g[k * HE + nt * 16 + i_col] : 0.f;
      v[j] = (short)f2bf(f);
    }
    w1f[nt] = v;
    scv[nt] = scs[nt * 16 + i_col];
    c1v[nt] = c1s[nt * 16 + i_col];
  }

  f32x4 acc = {0.f, 0.f, 0.f, 0.f};
  float xs = 0.f;

  int p = 0;
  for (int base = p0; base < p1; base += 64) {
    {
      const int er = base + w * 16 + i_col;
      short8v ae;
      if (kq < 2) {
        ae = *reinterpret_cast<const short8v*>(&exb[(size_t)er * 32 + kq * 8]);
      } else {
#pragma unroll
        for (int j = 0; j < 8; ++j) ae[j] = 0;
      }
      const f32x4 zero4 = {0.f, 0.f, 0.f, 0.f};
#pragma unroll
      for (int nt = 0; nt < 4; ++nt) {
        const f32x4 hv = __builtin_amdgcn_mfma_f32_16x16x32_bf16(
            ae, w1f[nt], zero4, 0, 0, 0);
        short4 sv;
        {
          const int e0 = base + w * 16 + kq * 4;
          const float h0 = (e0 + 0 < p1) ? fmaxf(fmaf(hv[0], scv[nt], c1v[nt]), 0.f) : 0.f;
          const float h1 = (e0 + 1 < p1) ? fmaxf(fmaf(hv[1], scv[nt], c1v[nt]), 0.f) : 0.f;
          const float h2 = (e0 + 2 < p1) ? fmaxf(fmaf(hv[2], scv[nt], c1v[nt]), 0.f) : 0.f;
          const float h3 = (e0 + 3 < p1) ? fmaxf(fmaf(hv[3], scv[nt], c1v[nt]), 0.f) : 0.f;
          sv.x = (short)f2bf(h0);
          sv.y = (short)f2bf(h1);
          sv.z = (short)f2bf(h2);
          sv.w = (short)f2bf(h3);
        }
        *reinterpret_cast<short4*>(
            &hnT[p][(nt * 16 + i_col) * HNST + w * 16 + kq * 4]) = sv;
      }
    }
    {
      const int et = tid >> 2, iq = tid & 3;
      const int er = base + et;
      short4 xv = {0, 0, 0, 0};
      if (er < p1)
        xv = *reinterpret_cast<const short4*>(
            &exb[(size_t)er * 32 + 16 + iq * 4]);
      xT[p][(iq * 4 + 0) * HNST + et] = xv.x;
      xT[p][(iq * 4 + 1) * HNST + et] = xv.y;
      xT[p][(iq * 4 + 2) * HNST + et] = xv.z;
      xT[p][(iq * 4 + 3) * HNST + et] = xv.w;
    }
    __syncthreads();
#pragma unroll
    for (int ks = 0; ks < 2; ++ks) {
      const short8v a = *reinterpret_cast<const short8v*>(
          &hnT[p][(w * 16 + i_col) * HNST + ks * 32 + kq * 8]);
      const short8v b = *reinterpret_cast<const short8v*>(
          &xT[p][i_col * HNST + ks * 32 + kq * 8]);
      acc = __builtin_amdgcn_mfma_f32_16x16x32_bf16(a, b, acc, 0, 0, 0);
      if (w == 0) {
#pragma unroll
        for (int j = 0; j < 8; ++j) xs += bf2f(b[j]);
      }
    }
    p ^= 1;
  }

  // coalesced partial writes: lane holds S[c = w*16+kq*4+r][i = i_col]
#pragma unroll
  for (int r = 0; r < 4; ++r)
    Spart[(size_t)blockIdx.x * 1024 + (w * 16 + kq * 4 + r) * 16 + i_col] =
        acc[r];
  if (w == 0) {
    xs += __shfl_xor(xs, 16, 64);
    xs += __shfl_xor(xs, 32, 64);
    if (kq == 0) XSpart[blockIdx.x * 16 + i_col] = xs;
  }
}

// ---------------------------------------------------------------------------
// Kernel 5: fuse (unchanged, SPLIT=8).
// ---------------------------------------------------------------------------
__global__ __launch_bounds__(256) void fuse_k(
    const float* __restrict__ Spart, const float* __restrict__ XSpart,
    const float* __restrict__ W2g, const float* __restrict__ b2g,
    const float* __restrict__ XN, const float* __restrict__ cnt,
    const float* __restrict__ rootg, const float* __restrict__ biasg,
    const float* __restrict__ A1, const float* __restrict__ ab1,
    const float* __restrict__ A2, const float* __restrict__ ab2,
    float* __restrict__ out) {
  __shared__ float S_l[1024];
  __shared__ float xs_l[16];
  __shared__ float xn_f[16];
  __shared__ float pooled[OUT_NODE];
  __shared__ float a_s[HA];
  __shared__ float red[16][N_ACT];

  const int g = blockIdx.x;
  const int tid = threadIdx.x, lane = tid & 63, w = tid >> 6;

  for (int t = tid; t < 1024; t += 256) {
    float s = 0.f;
#pragma unroll
    for (int q = 0; q < SPLIT; ++q)
      s += Spart[(size_t)(SPLIT * g + q) * 1024 + t];
    S_l[t] = s;
  }
  if (tid < 16) {
    float s = 0.f;
#pragma unroll
    for (int q = 0; q < SPLIT; ++q) s += XSpart[(SPLIT * g + q) * 16 + tid];
    xs_l[tid] = s;
    xn_f[tid] = XN[g * IN_NODE + tid];
  }
  __syncthreads();

  const float invc = 1.f / fmaxf(cnt[g], 1.f);
#pragma unroll
  for (int oi = 0; oi < 5; ++oi) {
    const int o = w * 5 + oi;
    float s = 0.f;
#pragma unroll
    for (int j = 0; j < 16; ++j) {
      const int u = lane + 64 * j;
      const int c = u >> 4, i = u & 15;
      s = fmaf(S_l[u], W2g[c * (IN_NODE * OUT_NODE) + i * OUT_NODE + o], s);
    }
    if (lane < 16) {
      s = fmaf(xs_l[lane], b2g[lane * OUT_NODE + o], s);
      s = fmaf(xn_f[lane], rootg[lane * OUT_NODE + o], s);
    }
    ROW_SUM16(s);
    s += __shfl_xor(s, 16, 64);
    s += __shfl_xor(s, 32, 64);
    if (lane == 0) pooled[o] = s * invc + biasg[o];
  }
  __syncthreads();

  {
    float v = ab1[tid];
#pragma unroll
    for (int k = 0; k < OUT_NODE; ++k)
      v = fmaf(pooled[k], A1[k * HA + tid], v);
    a_s[tid] = fmaxf(v, 0.f);
  }
  __syncthreads();
  {
    const int j = tid & 15, seg = tid >> 4;
    float v = 0.f;
#pragma unroll
    for (int kk = 0; kk < 16; ++kk) {
      const int k = seg * 16 + kk;
      v += a_s[k] * A2[k * N_ACT + j];
    }
    red[seg][j] = v;
  }
  __syncthreads();
  if (tid < N_ACT) {
    float s = ab2[tid];
#pragma unroll
    for (int seg = 0; seg < 16; ++seg) s += red[seg][tid];
    out[g * N_ACT + tid] = s;
  }
}

// ---------------------------------------------------------------------------
extern "C" void kernel_launch(void* const* d_in, const int* in_sizes, int n_in,
                              void* d_out, int out_size, void* d_ws,
                              size_t ws_size, hipStream_t stream) {
  const float* x     = (const float*)d_in[0];
  const int*   ei    = (const int*)d_in[1];
  const float* ea    = (const float*)d_in[2];
  const int*   batch = (const int*)d_in[3];
  const float* W1    = (const float*)d_in[4];
  const float* b1    = (const float*)d_in[5];
  const float* gamma = (const float*)d_in[6];
  const float* beta  = (const float*)d_in[7];
  const float* W2    = (const float*)d_in[8];
  const float* b2    = (const float*)d_in[9];
  const float* root  = (const float*)d_in[10];
  const float* bias  = (const float*)d_in[11];
  const float* A1    = (const float*)d_in[12];
  const float* ab1   = (const float*)d_in[13];
  const float* A2    = (const float*)d_in[14];
  const float* ab2   = (const float*)d_in[15];
  float* out = (float*)d_out;

  float* ws = (float*)d_ws;
  int*   iw = (int*)d_ws;
  // word offsets (R18 layout verbatim)
  float* hdr     = ws;                 // [0:128)
  float* scale   = ws + 128;           // [128:192)
  float* c1      = ws + 192;           // [192:256)
  float* XN      = ws + 256;           // [256:2304)
  float* cntb    = ws + 2304;          // [2304:2432)
  // --- zero_k covers words [0, 2560) ---
  int*   hist    = iw + 2704;          // [2704:2832)
  int*   cnt2dT  = iw + 2848;          // 128*NB = 100096 (slot to 202912)
  int*   off2dT  = iw + 202912;        // 100096 (slot to 402976)
  float* Spart   = ws + 402976;        // 1024*1024 (slot to 2500128)
  float* XSpart  = ws + 2500128;       // 1024*16  (slot to 2532896)
  unsigned short* exb = (unsigned short*)(iw + 2532896);  // 400064*32 shorts
  int*   ge      = iw + 402976;        // aliases Spart; consumed by scatter
                                       // before s_kernel overwrites (stream)

  zero_k<<<10, 256, 0, stream>>>(ws);
  gramcount_k<<<GB + NB, 256, 0, stream>>>(ea, ei, batch, hdr, ge, cnt2dT);
  colscanfin_k<<<N_GRAPHS + 1, 128, 0, stream>>>(cnt2dT, off2dT, hist, hdr,
                                                 W1, b1, gamma, beta, scale,
                                                 c1);
  scatxsum_k<<<NB + XB, 256, 0, stream>>>(ea, ei, ge, x, off2dT, hist, exb,
                                          batch, XN, cntb);
  s_kernel<<<N_GRAPHS * SPLIT, 256, 0, stream>>>(exb, W1, scale, c1, hist,
                                                 Spart, XSpart);
  fuse_k<<<N_GRAPHS, 256, 0, stream>>>(Spart, XSpart, W2, b2, XN, cntb, root,
                                       bias, A1, ab1, A2, ab2, out);
}

// Round 20
// 70.657 us; speedup vs baseline: 1.1884x; 1.0826x over previous
//
#include <hip/hip_runtime.h>

#define N_NODES   50000
#define N_EDGES   400000
#define IN_NODE   16
#define OUT_NODE  20
#define IN_EDGE   10
#define HE        64
#define HA        256
#define N_ACT     16
#define N_GRAPHS  128
#define BN_EPS    1e-5f
#define HNST      68          // LDS row stride (shorts) for hnT/xT
#define SPLIT     8           // S-kernel blocks per graph
#define NB        782         // count/scatter blocks (2 edges/thread)
#define SEG2      200192      // NB*256; 2 segments cover N_EDGES
#define NCH       13          // colscan chunks: 13*64 >= NB
#define GB        256         // gram blocks
#define XB        196         // xsum blocks: 196*256 >= N_NODES

typedef __attribute__((ext_vector_type(8))) short short8v;
typedef __attribute__((ext_vector_type(4))) float f32x4;

__device__ __forceinline__ unsigned short f2bf(float f) {
  unsigned u = __float_as_uint(f);
  u += 0x7fffu + ((u >> 16) & 1u);  // RNE
  return (unsigned short)(u >> 16);
}
__device__ __forceinline__ float bf2f(short s) {
  return __uint_as_float(((unsigned)(unsigned short)s) << 16);
}

#define DPP_ROR_ADD(v, CTRL)                                                  \
  ((v) + __int_as_float(__builtin_amdgcn_update_dpp(                          \
             0, __float_as_int(v), (CTRL), 0xF, 0xF, true)))
#define ROW_SUM16(v)                                                          \
  do {                                                                        \
    v = DPP_ROR_ADD(v, 0x128);                                                \
    v = DPP_ROR_ADD(v, 0x124);                                                \
    v = DPP_ROR_ADD(v, 0x122);                                                \
    v = DPP_ROR_ADD(v, 0x121);                                                \
  } while (0)

// Single-wave 128-entry exclusive scan of hist -> sb[0..128] (R19-proven).
__device__ __forceinline__ void wave_scan_hist(const int* __restrict__ hist,
                                               int* __restrict__ sb,
                                               int lane) {
  const int h0 = hist[lane];
  const int h1 = hist[64 + lane];
  int s0 = h0;
#pragma unroll
  for (int off = 1; off < 64; off <<= 1) {
    const int y = __shfl_up(s0, off, 64);
    if (lane >= off) s0 += y;
  }
  const int tot0 = __shfl(s0, 63, 64);
  int s1 = h1;
#pragma unroll
  for (int off = 1; off < 64; off <<= 1) {
    const int y = __shfl_up(s1, off, 64);
    if (lane >= off) s1 += y;
  }
  sb[lane] = s0 - h0;
  sb[64 + lane] = tot0 + s1 - h1;
  if (lane == 63) sb[128] = tot0 + s1;
}

// ---------------------------------------------------------------------------
// Kernel 1 (gram ∥ count). R20: gram writes per-block PARTIALS (plain
// stores, no atomics -> no pre-zero dispatch needed).
// ---------------------------------------------------------------------------
__global__ __launch_bounds__(256) void gramcount_k(
    const float* __restrict__ ea, const int* __restrict__ ei,
    const int* __restrict__ batch, float* __restrict__ gpart,
    int* __restrict__ ge, int* __restrict__ cnt2dT) {
  __shared__ float red[4][72];
  __shared__ int lh[N_GRAPHS];
  const int tid = threadIdx.x;

  if (blockIdx.x < GB) {
    float cs[10];
    float gm[55];
#pragma unroll
    for (int a = 0; a < 10; ++a) cs[a] = 0.f;
#pragma unroll
    for (int u = 0; u < 55; ++u) gm[u] = 0.f;

    for (int e = blockIdx.x * 256 + tid; e < N_EDGES; e += GB * 256) {
      const float2* rp = reinterpret_cast<const float2*>(ea + (size_t)e * 10);
      float f[10];
#pragma unroll
      for (int p = 0; p < 5; ++p) {
        const float2 t = rp[p];
        f[2 * p] = t.x;
        f[2 * p + 1] = t.y;
      }
#pragma unroll
      for (int a = 0; a < 10; ++a) cs[a] += f[a];
      int idx = 0;
#pragma unroll
      for (int a = 0; a < 10; ++a)
#pragma unroll
        for (int b = a; b < 10; ++b) {
          gm[idx] = fmaf(f[a], f[b], gm[idx]);
          ++idx;
        }
    }

#pragma unroll
    for (int v = 0; v < 10; ++v)
#pragma unroll
      for (int off = 1; off < 64; off <<= 1)
        cs[v] += __shfl_xor(cs[v], off, 64);
#pragma unroll
    for (int u = 0; u < 55; ++u)
#pragma unroll
      for (int off = 1; off < 64; off <<= 1)
        gm[u] += __shfl_xor(gm[u], off, 64);

    const int lane = tid & 63;
    const int w = tid >> 6;
    if (lane == 0) {
#pragma unroll
      for (int v = 0; v < 10; ++v) red[w][v] = cs[v];
#pragma unroll
      for (int u = 0; u < 55; ++u) red[w][10 + u] = gm[u];
    }
    __syncthreads();
    if (tid < 65) {
      const float s = red[0][tid] + red[1][tid] + red[2][tid] + red[3][tid];
      gpart[blockIdx.x * 72 + tid] = s;  // plain store, no atomics
    }
    return;
  }

  const int b = blockIdx.x - GB;
  if (tid < N_GRAPHS) lh[tid] = 0;
  __syncthreads();
#pragma unroll
  for (int j = 0; j < 2; ++j) {
    const int e = b * 256 + tid + j * SEG2;
    if (e < N_EDGES) {
      const int g = batch[ei[N_EDGES + e]];
      ge[e] = g;
      atomicAdd(&lh[g], 1);
    }
  }
  __syncthreads();
  if (tid < N_GRAPHS) cnt2dT[tid * NB + b] = lh[tid];
}

// ---------------------------------------------------------------------------
// Kernel 2 (colscan ∥ {gram-reduce + BN-finalize + XN/cnt zero}).
// Blocks [0,128): colscan of cnt2dT rows. Block 128: reduce gpart ->
// hdr_s (LDS), BN finalize -> scale/c1, and zero XN/cnt (plain stores,
// strictly before scatxsum's atomics in stream order).
// ---------------------------------------------------------------------------
__global__ __launch_bounds__(128) void colscanfin_k(
    const int* __restrict__ cnt2dT, int* __restrict__ off2dT,
    int* __restrict__ hist, const float* __restrict__ gpart,
    const float* __restrict__ W1, const float* __restrict__ b1,
    const float* __restrict__ gamma, const float* __restrict__ beta,
    float* __restrict__ scale, float* __restrict__ c1out,
    float* __restrict__ XN, float* __restrict__ cnt) {
  const int t = threadIdx.x;
  if (blockIdx.x < N_GRAPHS) {
    if (t >= 64) return;
    const int g = blockIdx.x;
    int vals[NCH];
#pragma unroll
    for (int c = 0; c < NCH; ++c) {
      const int b = c * 64 + t;
      vals[c] = (b < NB) ? cnt2dT[g * NB + b] : 0;
    }
    int running = 0;
#pragma unroll
    for (int c = 0; c < NCH; ++c) {
      int s = vals[c];
#pragma unroll
      for (int off = 1; off < 64; off <<= 1) {
        const int y = __shfl_up(s, off, 64);
        if (t >= off) s += y;
      }
      const int b = c * 64 + t;
      if (b < NB) off2dT[g * NB + b] = running + s - vals[c];  // exclusive
      running += __shfl(s, 63, 64);
    }
    if (t == 0) hist[g] = running;
    return;
  }

  // block 128: zero XN/cnt; reduce gram partials; BN finalize.
  __shared__ float hdr_s[72];
  for (int i = t; i < N_GRAPHS * IN_NODE; i += 128) XN[i] = 0.f;
  if (t < N_GRAPHS) cnt[t] = 0.f;
  if (t < 65) {
    float s = 0.f;
    for (int b = 0; b < GB; ++b) s += gpart[b * 72 + t];
    hdr_s[(t < 10) ? t : 6 + t] = s;  // colsum [0:10), gram [16:71)
  }
  __syncthreads();

  if (t < HE) {
    const int c = t;
    float wc[10];
#pragma unroll
    for (int k = 0; k < 10; ++k) wc[k] = W1[k * HE + c];
    float su = 0.f;
#pragma unroll
    for (int k = 0; k < 10; ++k) su = fmaf(hdr_s[k], wc[k], su);
    float q = 0.f;
    int idx = 0;
#pragma unroll
    for (int a = 0; a < 10; ++a) {
      q = fmaf(hdr_s[16 + idx], wc[a] * wc[a], q);
      ++idx;
#pragma unroll
      for (int b = a + 1; b < 10; ++b) {
        q = fmaf(2.f * hdr_s[16 + idx], wc[a] * wc[b], q);
        ++idx;
      }
    }
    const float b1c = b1[c];
    const float invE = 1.f / (float)N_EDGES;
    const float mu = su * invE + b1c;
    const float Eh2 = (q + 2.f * b1c * su) * invE + b1c * b1c;
    const float var = Eh2 - mu * mu;
    const float sc = gamma[c] * rsqrtf(var + BN_EPS);
    scale[c] = sc;
    c1out[c] = sc * (b1c - mu) + beta[c];
  }
}

// ---------------------------------------------------------------------------
// Kernel 3 (scatter ∥ xsum; R19-proven, single-wave hist scan).
// ---------------------------------------------------------------------------
__global__ __launch_bounds__(256) void scatxsum_k(
    const float* __restrict__ ea, const int* __restrict__ ei,
    const int* __restrict__ ge, const float* __restrict__ x,
    const int* __restrict__ off2dT, const int* __restrict__ hist,
    unsigned short* __restrict__ exb, const int* __restrict__ batch,
    float* __restrict__ XN, float* __restrict__ cnt) {
  const int tid = threadIdx.x;
  if (blockIdx.x < NB) {
    __shared__ int lh[N_GRAPHS];
    __shared__ int sb[N_GRAPHS + 1];
    __shared__ int obase[N_GRAPHS];
    const int b = blockIdx.x;
    if (tid < N_GRAPHS) lh[tid] = 0;
    if (tid < 64) wave_scan_hist(hist, sb, tid);
    __syncthreads();
    if (tid < N_GRAPHS) obase[tid] = sb[tid] + off2dT[tid * NB + b];

    int gj[2], lr[2];
#pragma unroll
    for (int j = 0; j < 2; ++j) {
      const int e = b * 256 + tid + j * SEG2;
      gj[j] = -1;
      lr[j] = 0;
      if (e < N_EDGES) {
        const int g = ge[e];
        gj[j] = g;
        lr[j] = atomicAdd(&lh[g], 1);
      }
    }
    __syncthreads();

#pragma unroll
    for (int j = 0; j < 2; ++j) {
      if (gj[j] < 0) continue;
      const int e = b * 256 + tid + j * SEG2;
      const float2* rp = reinterpret_cast<const float2*>(ea + (size_t)e * 10);
      float f[10];
#pragma unroll
      for (int p = 0; p < 5; ++p) {
        const float2 t2 = rp[p];
        f[2 * p] = t2.x;
        f[2 * p + 1] = t2.y;
      }
      const int s = ei[e];
      const float4* xp =
          reinterpret_cast<const float4*>(&x[(size_t)s * IN_NODE]);
      const float4 x0 = xp[0], x1 = xp[1], x2 = xp[2], x3 = xp[3];

      unsigned u[16];
      u[0] = f2bf(f[0]) | ((unsigned)f2bf(f[1]) << 16);
      u[1] = f2bf(f[2]) | ((unsigned)f2bf(f[3]) << 16);
      u[2] = f2bf(f[4]) | ((unsigned)f2bf(f[5]) << 16);
      u[3] = f2bf(f[6]) | ((unsigned)f2bf(f[7]) << 16);
      u[4] = f2bf(f[8]) | ((unsigned)f2bf(f[9]) << 16);
      u[5] = 0; u[6] = 0; u[7] = 0;
      u[8]  = f2bf(x0.x) | ((unsigned)f2bf(x0.y) << 16);
      u[9]  = f2bf(x0.z) | ((unsigned)f2bf(x0.w) << 16);
      u[10] = f2bf(x1.x) | ((unsigned)f2bf(x1.y) << 16);
      u[11] = f2bf(x1.z) | ((unsigned)f2bf(x1.w) << 16);
      u[12] = f2bf(x2.x) | ((unsigned)f2bf(x2.y) << 16);
      u[13] = f2bf(x2.z) | ((unsigned)f2bf(x2.w) << 16);
      u[14] = f2bf(x3.x) | ((unsigned)f2bf(x3.y) << 16);
      u[15] = f2bf(x3.z) | ((unsigned)f2bf(x3.w) << 16);

      const int pos = obase[gj[j]] + lr[j];
      int4* dst = reinterpret_cast<int4*>(exb + (size_t)pos * 32);
      dst[0] = int4{(int)u[0], (int)u[1], (int)u[2], (int)u[3]};
      dst[1] = int4{(int)u[4], (int)u[5], (int)u[6], (int)u[7]};
      dst[2] = int4{(int)u[8], (int)u[9], (int)u[10], (int)u[11]};
      dst[3] = int4{(int)u[12], (int)u[13], (int)u[14], (int)u[15]};
    }
    return;
  }

  // ---- xsum part ----
  __shared__ float xn_l[N_GRAPHS * IN_NODE];
  __shared__ float cnt_l[N_GRAPHS];
  const int lane = tid & 63;
  for (int t = tid; t < N_GRAPHS * IN_NODE; t += 256) xn_l[t] = 0.f;
  if (tid < N_GRAPHS) cnt_l[tid] = 0.f;
  __syncthreads();

  const int n = (blockIdx.x - NB) * 256 + tid;
  const bool valid = n < N_NODES;
  int g = -1;
  float xf[IN_NODE];
  if (valid) {
    g = batch[n];
    const float4* xp = reinterpret_cast<const float4*>(&x[(size_t)n * IN_NODE]);
    const float4 a0 = xp[0], a1 = xp[1], a2 = xp[2], a3 = xp[3];
    xf[0] = a0.x;  xf[1] = a0.y;  xf[2] = a0.z;  xf[3] = a0.w;
    xf[4] = a1.x;  xf[5] = a1.y;  xf[6] = a1.z;  xf[7] = a1.w;
    xf[8] = a2.x;  xf[9] = a2.y;  xf[10] = a2.z; xf[11] = a2.w;
    xf[12] = a3.x; xf[13] = a3.y; xf[14] = a3.z; xf[15] = a3.w;
  } else {
#pragma unroll
    for (int i = 0; i < IN_NODE; ++i) xf[i] = 0.f;
  }

  const int g0 = __builtin_amdgcn_readfirstlane(g);
  const bool uni = (__ballot(valid && (g == g0)) == 0xFFFFFFFFFFFFFFFFull);

  if (uni) {
#pragma unroll
    for (int i = 0; i < IN_NODE; ++i) {
      float s = xf[i];
      ROW_SUM16(s);
      s += __shfl_xor(s, 16, 64);
      s += __shfl_xor(s, 32, 64);
      xf[i] = s;
    }
    if (lane == 0) {
#pragma unroll
      for (int i = 0; i < IN_NODE; ++i)
        atomicAdd(&xn_l[g0 * IN_NODE + i], xf[i]);
      atomicAdd(&cnt_l[g0], 64.f);
    }
  } else if (valid) {
#pragma unroll
    for (int i = 0; i < IN_NODE; ++i) atomicAdd(&xn_l[g * IN_NODE + i], xf[i]);
    atomicAdd(&cnt_l[g], 1.f);
  }
  __syncthreads();

  if (tid < N_GRAPHS && cnt_l[tid] != 0.f) atomicAdd(&cnt[tid], cnt_l[tid]);
  for (int t = tid; t < N_GRAPHS * IN_NODE; t += 256) {
    const float v = xn_l[t];
    if (v != 0.f) atomicAdd(&XN[t], v);
  }
}

// ---------------------------------------------------------------------------
// Kernel 4: S accumulation (R19-proven: single-wave hist scan, SPLIT=8).
// ---------------------------------------------------------------------------
__global__ __launch_bounds__(256, 4) void s_kernel(
    const unsigned short* __restrict__ exb, const float* __restrict__ W1g,
    const float* __restrict__ scale, const float* __restrict__ c1g,
    const int* __restrict__ hist, float* __restrict__ Spart,
    float* __restrict__ XSpart) {
  __shared__ short hnT[2][64 * HNST];  // [c][e]
  __shared__ short xT[2][16 * HNST];   // [i][e]
  __shared__ float scs[HE], c1s[HE];
  __shared__ int sb[N_GRAPHS + 1];

  const int tid = threadIdx.x;
  const int lane = tid & 63;
  const int w = tid >> 6;
  const int i_col = lane & 15;
  const int kq = lane >> 4;

  if (tid < HE) {
    scs[tid] = scale[tid];
    c1s[tid] = c1g[tid];
  } else if (tid >= 64 && tid < 128) {
    wave_scan_hist(hist, sb, lane);
  }
  __syncthreads();

  const int g = blockIdx.x / SPLIT;
  const int pp = blockIdx.x - g * SPLIT;
  const int gs = sb[g], geE = sb[g + 1];
  const int cnt = geE - gs;
  const int p0 = gs + (cnt * pp) / SPLIT;
  const int p1 = gs + (cnt * (pp + 1)) / SPLIT;

  short8v w1f[4];
  float scv[4], c1v[4];
#pragma unroll
  for (int nt = 0; nt < 4; ++nt) {
    short8v v;
#pragma unroll
    for (int j = 0; j < 8; ++j) {
      const int k = kq * 8 + j;
      const float f = (k < IN_EDGE) ? W1g[k * HE + nt * 16 + i_col] : 0.f;
      v[j] = (short)f2bf(f);
    }
    w1f[nt] = v;
    scv[nt] = scs[nt * 16 + i_col];
    c1v[nt] = c1s[nt * 16 + i_col];
  }

  f32x4 acc = {0.f, 0.f, 0.f, 0.f};
  float xs = 0.f;

  int p = 0;
  for (int base = p0; base < p1; base += 64) {
    {
      const int er = base + w * 16 + i_col;
      short8v ae;
      if (kq < 2) {
        ae = *reinterpret_cast<const short8v*>(&exb[(size_t)er * 32 + kq * 8]);
      } else {
#pragma unroll
        for (int j = 0; j < 8; ++j) ae[j] = 0;
      }
      const f32x4 zero4 = {0.f, 0.f, 0.f, 0.f};
#pragma unroll
      for (int nt = 0; nt < 4; ++nt) {
        const f32x4 hv = __builtin_amdgcn_mfma_f32_16x16x32_bf16(
            ae, w1f[nt], zero4, 0, 0, 0);
        short4 sv;
        {
          const int e0 = base + w * 16 + kq * 4;
          const float h0 = (e0 + 0 < p1) ? fmaxf(fmaf(hv[0], scv[nt], c1v[nt]), 0.f) : 0.f;
          const float h1 = (e0 + 1 < p1) ? fmaxf(fmaf(hv[1], scv[nt], c1v[nt]), 0.f) : 0.f;
          const float h2 = (e0 + 2 < p1) ? fmaxf(fmaf(hv[2], scv[nt], c1v[nt]), 0.f) : 0.f;
          const float h3 = (e0 + 3 < p1) ? fmaxf(fmaf(hv[3], scv[nt], c1v[nt]), 0.f) : 0.f;
          sv.x = (short)f2bf(h0);
          sv.y = (short)f2bf(h1);
          sv.z = (short)f2bf(h2);
          sv.w = (short)f2bf(h3);
        }
        *reinterpret_cast<short4*>(
            &hnT[p][(nt * 16 + i_col) * HNST + w * 16 + kq * 4]) = sv;
      }
    }
    {
      const int et = tid >> 2, iq = tid & 3;
      const int er = base + et;
      short4 xv = {0, 0, 0, 0};
      if (er < p1)
        xv = *reinterpret_cast<const short4*>(
            &exb[(size_t)er * 32 + 16 + iq * 4]);
      xT[p][(iq * 4 + 0) * HNST + et] = xv.x;
      xT[p][(iq * 4 + 1) * HNST + et] = xv.y;
      xT[p][(iq * 4 + 2) * HNST + et] = xv.z;
      xT[p][(iq * 4 + 3) * HNST + et] = xv.w;
    }
    __syncthreads();
#pragma unroll
    for (int ks = 0; ks < 2; ++ks) {
      const short8v a = *reinterpret_cast<const short8v*>(
          &hnT[p][(w * 16 + i_col) * HNST + ks * 32 + kq * 8]);
      const short8v b = *reinterpret_cast<const short8v*>(
          &xT[p][i_col * HNST + ks * 32 + kq * 8]);
      acc = __builtin_amdgcn_mfma_f32_16x16x32_bf16(a, b, acc, 0, 0, 0);
      if (w == 0) {
#pragma unroll
        for (int j = 0; j < 8; ++j) xs += bf2f(b[j]);
      }
    }
    p ^= 1;
  }

  // coalesced partial writes: lane holds S[c = w*16+kq*4+r][i = i_col]
#pragma unroll
  for (int r = 0; r < 4; ++r)
    Spart[(size_t)blockIdx.x * 1024 + (w * 16 + kq * 4 + r) * 16 + i_col] =
        acc[r];
  if (w == 0) {
    xs += __shfl_xor(xs, 16, 64);
    xs += __shfl_xor(xs, 32, 64);
    if (kq == 0) XSpart[blockIdx.x * 16 + i_col] = xs;
  }
}

// ---------------------------------------------------------------------------
// Kernel 5: fuse (unchanged, SPLIT=8).
// ---------------------------------------------------------------------------
__global__ __launch_bounds__(256) void fuse_k(
    const float* __restrict__ Spart, const float* __restrict__ XSpart,
    const float* __restrict__ W2g, const float* __restrict__ b2g,
    const float* __restrict__ XN, const float* __restrict__ cnt,
    const float* __restrict__ rootg, const float* __restrict__ biasg,
    const float* __restrict__ A1, const float* __restrict__ ab1,
    const float* __restrict__ A2, const float* __restrict__ ab2,
    float* __restrict__ out) {
  __shared__ float S_l[1024];
  __shared__ float xs_l[16];
  __shared__ float xn_f[16];
  __shared__ float pooled[OUT_NODE];
  __shared__ float a_s[HA];
  __shared__ float red[16][N_ACT];

  const int g = blockIdx.x;
  const int tid = threadIdx.x, lane = tid & 63, w = tid >> 6;

  for (int t = tid; t < 1024; t += 256) {
    float s = 0.f;
#pragma unroll
    for (int q = 0; q < SPLIT; ++q)
      s += Spart[(size_t)(SPLIT * g + q) * 1024 + t];
    S_l[t] = s;
  }
  if (tid < 16) {
    float s = 0.f;
#pragma unroll
    for (int q = 0; q < SPLIT; ++q) s += XSpart[(SPLIT * g + q) * 16 + tid];
    xs_l[tid] = s;
    xn_f[tid] = XN[g * IN_NODE + tid];
  }
  __syncthreads();

  const float invc = 1.f / fmaxf(cnt[g], 1.f);
#pragma unroll
  for (int oi = 0; oi < 5; ++oi) {
    const int o = w * 5 + oi;
    float s = 0.f;
#pragma unroll
    for (int j = 0; j < 16; ++j) {
      const int u = lane + 64 * j;
      const int c = u >> 4, i = u & 15;
      s = fmaf(S_l[u], W2g[c * (IN_NODE * OUT_NODE) + i * OUT_NODE + o], s);
    }
    if (lane < 16) {
      s = fmaf(xs_l[lane], b2g[lane * OUT_NODE + o], s);
      s = fmaf(xn_f[lane], rootg[lane * OUT_NODE + o], s);
    }
    ROW_SUM16(s);
    s += __shfl_xor(s, 16, 64);
    s += __shfl_xor(s, 32, 64);
    if (lane == 0) pooled[o] = s * invc + biasg[o];
  }
  __syncthreads();

  {
    float v = ab1[tid];
#pragma unroll
    for (int k = 0; k < OUT_NODE; ++k)
      v = fmaf(pooled[k], A1[k * HA + tid], v);
    a_s[tid] = fmaxf(v, 0.f);
  }
  __syncthreads();
  {
    const int j = tid & 15, seg = tid >> 4;
    float v = 0.f;
#pragma unroll
    for (int kk = 0; kk < 16; ++kk) {
      const int k = seg * 16 + kk;
      v += a_s[k] * A2[k * N_ACT + j];
    }
    red[seg][j] = v;
  }
  __syncthreads();
  if (tid < N_ACT) {
    float s = ab2[tid];
#pragma unroll
    for (int seg = 0; seg < 16; ++seg) s += red[seg][tid];
    out[g * N_ACT + tid] = s;
  }
}

// ---------------------------------------------------------------------------
extern "C" void kernel_launch(void* const* d_in, const int* in_sizes, int n_in,
                              void* d_out, int out_size, void* d_ws,
                              size_t ws_size, hipStream_t stream) {
  const float* x     = (const float*)d_in[0];
  const int*   ei    = (const int*)d_in[1];
  const float* ea    = (const float*)d_in[2];
  const int*   batch = (const int*)d_in[3];
  const float* W1    = (const float*)d_in[4];
  const float* b1    = (const float*)d_in[5];
  const float* gamma = (const float*)d_in[6];
  const float* beta  = (const float*)d_in[7];
  const float* W2    = (const float*)d_in[8];
  const float* b2    = (const float*)d_in[9];
  const float* root  = (const float*)d_in[10];
  const float* bias  = (const float*)d_in[11];
  const float* A1    = (const float*)d_in[12];
  const float* ab1   = (const float*)d_in[13];
  const float* A2    = (const float*)d_in[14];
  const float* ab2   = (const float*)d_in[15];
  float* out = (float*)d_out;

  float* ws = (float*)d_ws;
  int*   iw = (int*)d_ws;
  // word offsets (no pre-zeroed region anymore; all buffers fully written
  // before read: gpart by gram blocks, XN/cnt zeroed by colscanfin blk128)
  float* scale   = ws + 128;           // [128:192)
  float* c1      = ws + 192;           // [192:256)
  float* XN      = ws + 256;           // [256:2304)
  float* cntb    = ws + 2304;          // [2304:2432)
  int*   hist    = iw + 2704;          // [2704:2832)
  int*   cnt2dT  = iw + 2848;          // 128*NB = 100096 (slot to 202912)
  int*   off2dT  = iw + 202912;        // 100096 (slot to 303008)
  float* gpart   = ws + 303008;        // 256*72 = 18432 -> 321440
  float* Spart   = ws + 402976;        // 1024*1024 (slot to 2500128)
  float* XSpart  = ws + 2500128;       // 1024*16  (slot to 2532896)
  unsigned short* exb = (unsigned short*)(iw + 2532896);  // 400064*32 shorts
  int*   ge      = iw + 402976;        // aliases Spart; consumed by scatter
                                       // before s_kernel overwrites (stream)

  gramcount_k<<<GB + NB, 256, 0, stream>>>(ea, ei, batch, gpart, ge, cnt2dT);
  colscanfin_k<<<N_GRAPHS + 1, 128, 0, stream>>>(cnt2dT, off2dT, hist, gpart,
                                                 W1, b1, gamma, beta, scale,
                                                 c1, XN, cntb);
  scatxsum_k<<<NB + XB, 256, 0, stream>>>(ea, ei, ge, x, off2dT, hist, exb,
                                          batch, XN, cntb);
  s_kernel<<<N_GRAPHS * SPLIT, 256, 0, stream>>>(exb, W1, scale, c1, hist,
                                                 Spart, XSpart);
  fuse_k<<<N_GRAPHS, 256, 0, stream>>>(Spart, XSpart, W2, b2, XN, cntb, root,
                                       bias, A1, ab1, A2, ab2, out);
}